// Round 4
// baseline (6405.509 us; speedup 1.0000x reference)
//
#include <hip/hip_runtime.h>
#include <hip/hip_bf16.h>
#include <stdint.h>

// ---------------- problem constants ----------------
#define NN      50000          // nodes
#define NPAD    50048          // 391 * 128
#define MT      391            // M tiles of 128
#define CC      128            // channels
#define NSPL    25             // spline kernel slots
#define NSLOT   26             // 25 spline slots + root
#define LAYERS  3
#define NWT     (LAYERS * NSLOT + 1)   // +1 = final linear weight block

typedef unsigned short ushort_t;
typedef __attribute__((ext_vector_type(8))) short bf16x8;
typedef __attribute__((ext_vector_type(4))) float f32x4;

__device__ __forceinline__ float b2f(uint32_t hi16) {
  union { uint32_t u; float f; } v; v.u = hi16 << 16; return v.f;
}
__device__ __forceinline__ ushort_t f2b(float f) {
  union { float f; uint32_t u; } v; v.f = f;
  uint32_t u = v.u;
  return (ushort_t)((u + 0x7fffu + ((u >> 16) & 1u)) >> 16);
}
// dtype-agnostic scalar load: bf ? bf16[i] : f32[i]
__device__ __forceinline__ float loadf(const void* p, size_t i, int bf) {
  return bf ? b2f(((const ushort_t*)p)[i]) : ((const float*)p)[i];
}

// ---------------- dtype probe ----------------
// bf16 data: bits[14:7] of a 32b word = exponent of the low bf16 (~127 for N(0,1)).
// fp32 data: bits[14:7] = mid-mantissa bits (uniform). 64 samples, threshold 48.
__global__ void probe_dtype(const uint32_t* __restrict__ emb_w, int* __restrict__ flag) {
  int l = threadIdx.x;
  uint32_t w = emb_w[l];
  int e = (w >> 7) & 0xff;
  int hit = (e >= 118 && e <= 134) ? 1 : 0;
  unsigned long long m = __ballot(hit);
  if (l == 0) *flag = (__popcll(m) >= 48) ? 1 : 0;
}

// ---------------- weight prep: transpose + hi/lo bf16 split ----------------
// block b < L*NSLOT: layer i=b/NSLOT, slot s=b%NSLOT:
//   Wt[b][c][j] = s<25 ? W[i][s][j][c] : root[i][j][c]
// block b == L*NSLOT: Wt[b][c][j] = finW[c][j]
__global__ void prep_wt(const void* __restrict__ W, const void* __restrict__ root,
                        const void* __restrict__ finW, const int* __restrict__ flag,
                        ushort_t* __restrict__ Whi, ushort_t* __restrict__ Wlo) {
  int idx = blockIdx.x * blockDim.x + threadIdx.x;
  const int total = NWT * CC * CC;
  if (idx >= total) return;
  int bf = *flag;
  int b  = idx / (CC * CC);
  int cj = idx % (CC * CC);
  int c  = cj >> 7, j = cj & 127;
  float v;
  if (b < LAYERS * NSLOT) {
    int i = b / NSLOT, s = b % NSLOT;
    v = (s < NSPL) ? loadf(W, ((size_t)(i * NSPL + s) * CC + j) * CC + c, bf)
                   : loadf(root, ((size_t)i * CC + j) * CC + c, bf);
  } else {
    v = loadf(finW, (size_t)c * CC + j, bf);   // h @ finW.T: already [c][j]
  }
  ushort_t hi = f2b(v);
  Whi[idx] = hi;
  Wlo[idx] = f2b(v - b2f(hi));
}

// ---------------- h0 = emb[x] -> h2 (hi|lo) ----------------
__global__ void init_h(const int* __restrict__ x, const void* __restrict__ emb,
                       const int* __restrict__ flag, ushort_t* __restrict__ h2) {
  int idx = blockIdx.x * blockDim.x + threadIdx.x;   // over NPAD*128
  int c = idx & 127, n = idx >> 7;
  if (n >= NPAD) return;
  float v = (n < NN) ? loadf(emb, (size_t)x[n] * CC + c, *flag) : 0.0f;
  ushort_t hi = f2b(v);
  h2[(size_t)n * 256 + c]       = hi;
  h2[(size_t)n * 256 + 128 + c] = f2b(v - b2f(hi));
}

// ---------------- degree ----------------
__global__ void deg_kernel(const int* __restrict__ ei, float* __restrict__ deg, int E) {
  int e = blockIdx.x * blockDim.x + threadIdx.x;
  if (e < E) unsafeAtomicAdd(&deg[ei[E + e]], 1.0f);
}
__global__ void rdeg_kernel(const float* __restrict__ deg, float* __restrict__ rdeg) {
  int n = blockIdx.x * blockDim.x + threadIdx.x;
  if (n < NPAD) rdeg[n] = 1.0f / fmaxf(deg[n], 1.0f);
}

// ---------------- split-precision MFMA GEMM ----------------
// A2: [NPAD][256] bf16 (hi:0..127 | lo:128..255). B: [slots][128][128] bf16 [c][j].
// acc = Ahi*Bhi + Alo*Bhi + Ahi*Blo  (3 K=128 chunks; drops lo*lo ~2^-18 rel).
// 128x128 tile/block, 4 waves in 64x64 quadrants, mfma_f32_16x16x32_bf16.
// MODE 0: tr bf16 (stride ldc). MODE 1: final -> d_out (dtype by flag) + bias.
// MODE 2: agg fp32 init = acc * max(deg,1)  (root term pre-scaled for mean-agg).
template <int MODE>
__global__ __launch_bounds__(256, 2) void gemm_split(
    const ushort_t* __restrict__ A2,
    const ushort_t* __restrict__ Bhi, const ushort_t* __restrict__ Blo,
    const void* __restrict__ bias, const int* __restrict__ flag,
    const float* __restrict__ deg,
    void* __restrict__ Cout, int ldc, int Mvalid) {
  __shared__ char sm[65536];
  char* smA = sm;
  char* smB = sm + 32768;
  const int m0   = blockIdx.x * 128;
  const int slot = blockIdx.y;
  const int tid = threadIdx.x;
  const int w = tid >> 6, l = tid & 63;
  const int lr = l & 15, lg = l >> 4;
  const int wr = w >> 1, wc = w & 1;

  f32x4 acc[4][4] = {};
#pragma unroll
  for (int ch = 0; ch < 3; ++ch) {
    const ushort_t* Ab = A2 + (ch == 1 ? 128 : 0);
    const ushort_t* Bb = (ch == 2 ? Blo : Bhi) + (size_t)slot * CC * CC;
    // stage A (row stride 256 elem) and B (row stride 128 elem) tiles
    for (int i = 0; i < 8; ++i) {
      int row    = w * 32 + i * 4 + lg;
      int gchunk = lr ^ (row & 7);                 // pre-swizzled global 16B chunk
      const ushort_t* gA = Ab + (size_t)(m0 + row) * 256 + gchunk * 8;
      const ushort_t* gB = Bb + (size_t)row * CC + gchunk * 8;
      __builtin_amdgcn_global_load_lds(
          (const __attribute__((address_space(1))) void*)gA,
          (__attribute__((address_space(3))) void*)(smA + (w * 32 + i * 4) * 256), 16, 0, 0);
      __builtin_amdgcn_global_load_lds(
          (const __attribute__((address_space(1))) void*)gB,
          (__attribute__((address_space(3))) void*)(smB + (w * 32 + i * 4) * 256), 16, 0, 0);
    }
    __syncthreads();

    for (int kk = 0; kk < 4; ++kk) {
      bf16x8 av[4], bv[4];
#pragma unroll
      for (int mi = 0; mi < 4; ++mi) {
        int row   = wr * 64 + mi * 16 + lr;
        int chunk = (kk * 4 + lg) ^ (row & 7);
        av[mi] = *(const bf16x8*)(smA + row * 256 + chunk * 16);
      }
#pragma unroll
      for (int ni = 0; ni < 4; ++ni) {
        int row   = wc * 64 + ni * 16 + lr;
        int chunk = (kk * 4 + lg) ^ (row & 7);
        bv[ni] = *(const bf16x8*)(smB + row * 256 + chunk * 16);
      }
#pragma unroll
      for (int mi = 0; mi < 4; ++mi)
#pragma unroll
        for (int ni = 0; ni < 4; ++ni)
          acc[mi][ni] = __builtin_amdgcn_mfma_f32_16x16x32_bf16(av[mi], bv[ni], acc[mi][ni], 0, 0, 0);
    }
    __syncthreads();   // before next chunk overwrites LDS
  }

  // epilogue; C/D layout: col = lane&15, row = (lane>>4)*4 + j
  const int bf = (MODE == 1) ? *flag : 0;
  const int colb = slot * 128 + wc * 64;
#pragma unroll
  for (int mi = 0; mi < 4; ++mi) {
    int growbase = m0 + wr * 64 + mi * 16 + lg * 4;
#pragma unroll
    for (int ni = 0; ni < 4; ++ni) {
      int col = colb + ni * 16 + lr;
      float badd = (MODE == 1) ? loadf(bias, col & 127, bf) : 0.0f;
      f32x4 v = acc[mi][ni];
#pragma unroll
      for (int j = 0; j < 4; ++j) {
        int grow = growbase + j;
        if (grow < Mvalid) {
          if (MODE == 0) {
            ((ushort_t*)Cout)[(size_t)grow * ldc + col] = f2b(v[j]);
          } else if (MODE == 2) {
            float dscale = fmaxf(deg[grow], 1.0f);
            ((float*)Cout)[(size_t)grow * ldc + col] = v[j] * dscale;
          } else {
            float val = v[j] + badd;
            if (bf) ((ushort_t*)Cout)[(size_t)grow * ldc + col] = f2b(val);
            else    ((float*)Cout)[(size_t)grow * ldc + col] = val;
          }
        }
      }
    }
  }
}

// ---------------- edge gather + atomic scatter (spline slots [s0g, s1g)) ----------------
__global__ __launch_bounds__(256) void edge_kernel(
    const int* __restrict__ ei, const void* __restrict__ eattr,
    const int* __restrict__ flag, const ushort_t* __restrict__ tr,
    float* __restrict__ agg, int E, int s0g, int s1g, int ldt) {
  int wid = (blockIdx.x * blockDim.x + threadIdx.x) >> 6;
  int l   = threadIdx.x & 63;
  int nw  = (gridDim.x * blockDim.x) >> 6;
  int bf  = *flag;
  for (int e = wid; e < E; e += nw) {
    int src = ei[e];
    int dst = ei[E + e];
    float a0, a1;
    if (bf) {
      uint32_t ap = ((const uint32_t*)eattr)[e];
      a0 = b2f(ap & 0xffffu); a1 = b2f(ap >> 16);
    } else {
      float2 f = ((const float2*)eattr)[e];
      a0 = f.x; a1 = f.y;
    }
    float v0 = fminf(fmaxf(a0 * 4.0f, 0.0f), 4.0f);   // sanitize (NaN -> 0)
    float v1 = fminf(fmaxf(a1 * 4.0f, 0.0f), 4.0f);
    float lo0 = fminf(floorf(v0), 3.0f);
    float lo1 = fminf(floorf(v1), 3.0f);
    float f0 = v0 - lo0, f1 = v1 - lo1;
    int base = (int)lo0 + 5 * (int)lo1;
    float w00 = (1.0f - f0) * (1.0f - f1);
    float w10 = f0 * (1.0f - f1);
    float w01 = (1.0f - f0) * f1;
    float w11 = f0 * f1;
    const ushort_t* trow = tr + (size_t)src * ldt + 2 * l;
    float sA = 0.0f, sB = 0.0f;
    int got = 0;
#define TAP(K, W)                                                          \
    if ((K) >= s0g && (K) < s1g) {                                         \
      uint32_t q = *(const uint32_t*)(trow + ((K) - s0g) * CC);            \
      sA += (W) * b2f(q & 0xffffu); sB += (W) * b2f(q >> 16); got = 1;     \
    }
    TAP(base,     w00)
    TAP(base + 1, w10)
    TAP(base + 5, w01)
    TAP(base + 6, w11)
#undef TAP
    if (got) {
      float* ar = agg + (size_t)dst * CC + 2 * l;
      unsafeAtomicAdd(ar, sA);
      unsafeAtomicAdd(ar + 1, sB);
    }
  }
}

// ---------------- node: y = agg*rdeg + bias (root already in agg) ; BN sums ----------------
__global__ __launch_bounds__(256) void node_bn(
    float* __restrict__ agg, const float* __restrict__ rdeg,
    const void* __restrict__ bias, int layer, const int* __restrict__ flag,
    float* __restrict__ bnsum, float* __restrict__ bnsq) {
  int c   = threadIdx.x & 127;
  int sub = threadIdx.x >> 7;
  float b = loadf(bias, (size_t)layer * CC + c, *flag);
  float lsum = 0.0f, lsq = 0.0f;
  for (int n = blockIdx.x * 2 + sub; n < NN; n += gridDim.x * 2) {
    float y = agg[(size_t)n * CC + c] * rdeg[n] + b;
    agg[(size_t)n * CC + c] = y;
    lsum += y; lsq += y * y;
  }
  __shared__ float ssum[256], ssq[256];
  ssum[threadIdx.x] = lsum; ssq[threadIdx.x] = lsq;
  __syncthreads();
  if (sub == 0) {
    unsafeAtomicAdd(&bnsum[c], ssum[c] + ssum[c + 128]);
    unsafeAtomicAdd(&bnsq[c],  ssq[c]  + ssq[c + 128]);
  }
}

__global__ void bn_final(const float* __restrict__ bnsum, const float* __restrict__ bnsq,
                         const void* __restrict__ gamma, const void* __restrict__ beta,
                         int layer, const int* __restrict__ flag,
                         float* __restrict__ scale, float* __restrict__ shift) {
  int c = threadIdx.x;
  int bf = *flag;
  float mean = bnsum[c] * (1.0f / NN);
  float var  = fmaxf(bnsq[c] * (1.0f / NN) - mean * mean, 0.0f);
  float sc = loadf(gamma, (size_t)layer * CC + c, bf) * rsqrtf(var + 1e-5f);
  scale[c] = sc;
  shift[c] = loadf(beta, (size_t)layer * CC + c, bf) - mean * sc;
}

template <bool RELU>
__global__ void norm_kernel(const float* __restrict__ y, const float* __restrict__ scale,
                            const float* __restrict__ shift, ushort_t* __restrict__ h2) {
  int idx = blockIdx.x * blockDim.x + threadIdx.x;   // over NPAD*128
  int c = idx & 127, n = idx >> 7;
  if (n >= NPAD) return;
  float v = 0.0f;
  if (n < NN) {
    v = scale[c] * y[idx] + shift[c];
    if (RELU) v = fmaxf(v, 0.0f);
  }
  ushort_t hi = f2b(v);
  h2[(size_t)n * 256 + c]       = hi;
  h2[(size_t)n * 256 + 128 + c] = f2b(v - b2f(hi));
}

// ---------------- launch ----------------
extern "C" void kernel_launch(void* const* d_in, const int* in_sizes, int n_in,
                              void* d_out, int out_size, void* d_ws, size_t ws_size,
                              hipStream_t stream) {
  const int*  x     = (const int*)d_in[0];
  const int*  ei    = (const int*)d_in[1];
  const void* eattr = d_in[2];
  const void* emb   = d_in[3];
  const void* convW = d_in[4];
  const void* convR = d_in[5];
  const void* convB = d_in[6];
  const void* gamma = d_in[7];
  const void* beta  = d_in[8];
  const void* finW  = d_in[9];
  const void* finB  = d_in[10];
  const int E = in_sizes[1] / 2;

  char* ws = (char*)d_ws;
  size_t off = 0;
  auto alloc = [&](size_t bytes) -> char* {
    char* p = ws + off; off += (bytes + 255) & ~(size_t)255; return p;
  };
  int*      flag = (int*)alloc(256);
  ushort_t* Whi  = (ushort_t*)alloc((size_t)NWT * CC * CC * 2);             // 2.6 MB
  ushort_t* Wlo  = (ushort_t*)alloc((size_t)NWT * CC * CC * 2);             // 2.6 MB
  ushort_t* h2   = (ushort_t*)alloc((size_t)NPAD * 256 * 2);                // 25.6 MB
  float*    agg  = (float*)alloc((size_t)NPAD * CC * 4);                    // 25.6 MB
  float*    deg  = (float*)alloc((size_t)NPAD * 4);
  float*    rdeg = (float*)alloc((size_t)NPAD * 4);
  float*    bnst = (float*)alloc(4 * CC * 4);   // sum | sq | scale | shift

  // tr: spg spline slots of [NPAD][128] bf16, processed in groups over 25 slots
  const size_t per_slot = (size_t)NPAD * CC * 2;                            // 12.8 MB
  size_t avail = (ws_size > off + 4096) ? (ws_size - off - 4096) : 0;
  int spg = (int)(avail / per_slot);
  if (spg > NSPL) spg = NSPL;
  if (spg < 1) spg = 1;
  int ngroups = (NSPL + spg - 1) / spg;
  spg = (NSPL + ngroups - 1) / ngroups;        // balance group sizes
  ushort_t* tr = (ushort_t*)(ws + off);
  const int ldt = spg * CC;

  probe_dtype<<<1, 64, 0, stream>>>((const uint32_t*)emb, flag);
  hipMemsetAsync(deg, 0, (size_t)NPAD * 4, stream);
  prep_wt<<<(NWT * CC * CC + 255) / 256, 256, 0, stream>>>(convW, convR, finW, flag, Whi, Wlo);
  init_h<<<(NPAD * CC) / 256, 256, 0, stream>>>(x, emb, flag, h2);
  deg_kernel<<<(E + 255) / 256, 256, 0, stream>>>(ei, deg, E);
  rdeg_kernel<<<(NPAD + 255) / 256, 256, 0, stream>>>(deg, rdeg);

  for (int i = 0; i < LAYERS; ++i) {
    hipMemsetAsync(bnst, 0, 2 * CC * 4, stream);
    // root term -> agg initializer (pre-scaled by max(deg,1); mean-agg divides it out)
    gemm_split<2><<<dim3(MT, 1), 256, 0, stream>>>(
        h2, Whi + ((size_t)i * NSLOT + NSPL) * CC * CC,
        Wlo + ((size_t)i * NSLOT + NSPL) * CC * CC,
        nullptr, flag, deg, agg, CC, NN);
    for (int g0 = 0; g0 < NSPL; g0 += spg) {
      int cnt = NSPL - g0 < spg ? NSPL - g0 : spg;
      gemm_split<0><<<dim3(MT, cnt), 256, 0, stream>>>(
          h2, Whi + ((size_t)i * NSLOT + g0) * CC * CC,
          Wlo + ((size_t)i * NSLOT + g0) * CC * CC,
          nullptr, flag, deg, tr, ldt, NPAD);
      edge_kernel<<<2048, 256, 0, stream>>>(ei, eattr, flag, tr, agg, E, g0, g0 + cnt, ldt);
    }
    node_bn<<<1024, 256, 0, stream>>>(agg, rdeg, convB, i, flag, bnst, bnst + 128);
    bn_final<<<1, 128, 0, stream>>>(bnst, bnst + 128, gamma, beta, i, flag,
                                    bnst + 256, bnst + 384);
    if (i < LAYERS - 1)
      norm_kernel<true><<<(NPAD * CC) / 256, 256, 0, stream>>>(agg, bnst + 256, bnst + 384, h2);
    else
      norm_kernel<false><<<(NPAD * CC) / 256, 256, 0, stream>>>(agg, bnst + 256, bnst + 384, h2);
  }
  gemm_split<1><<<dim3(MT, 1), 256, 0, stream>>>(
      h2, Whi + (size_t)LAYERS * NSLOT * CC * CC,
      Wlo + (size_t)LAYERS * NSLOT * CC * CC,
      finB, flag, deg, d_out, CC, NN);
}

// Round 5
// 2577.451 us; speedup vs baseline: 2.4852x; 2.4852x over previous
//
#include <hip/hip_runtime.h>
#include <hip/hip_bf16.h>
#include <stdint.h>

// ---------------- problem constants ----------------
#define NN      50000          // nodes
#define NPAD    50048          // 391 * 128
#define MT      391            // M tiles of 128
#define CC      128            // channels
#define NSPL    25             // spline kernel slots
#define KBIG    3200           // 25 * 128 contraction for U GEMM
#define LAYERS  3

typedef unsigned short ushort_t;
typedef __attribute__((ext_vector_type(8))) short bf16x8;
typedef __attribute__((ext_vector_type(4))) float f32x4;

__device__ __forceinline__ float b2f(uint32_t hi16) {
  union { uint32_t u; float f; } v; v.u = hi16 << 16; return v.f;
}
__device__ __forceinline__ ushort_t f2b(float f) {
  union { float f; uint32_t u; } v; v.f = f;
  uint32_t u = v.u;
  return (ushort_t)((u + 0x7fffu + ((u >> 16) & 1u)) >> 16);
}
__device__ __forceinline__ float loadf(const void* p, size_t i, int bf) {
  return bf ? b2f(((const ushort_t*)p)[i]) : ((const float*)p)[i];
}

// ---------------- dtype probe (bf16 vs fp32 inputs) ----------------
__global__ void probe_dtype(const uint32_t* __restrict__ emb_w, int* __restrict__ flag) {
  int l = threadIdx.x;
  uint32_t w = emb_w[l];
  int e = (w >> 7) & 0xff;
  int hit = (e >= 118 && e <= 134) ? 1 : 0;
  unsigned long long m = __ballot(hit);
  if (l == 0) *flag = (__popcll(m) >= 48) ? 1 : 0;
}

// ---------------- weight prep ----------------
// Wcat[i][c][k*128+j] = W[i][k][j][c], hi/lo bf16 planes. [LAYERS][128][3200]
__global__ void prep_wcat(const void* __restrict__ W, const int* __restrict__ flag,
                          ushort_t* __restrict__ Whi, ushort_t* __restrict__ Wlo) {
  int idx = blockIdx.x * blockDim.x + threadIdx.x;
  const int total = LAYERS * CC * KBIG;
  if (idx >= total) return;
  int bf = *flag;
  int i  = idx / (CC * KBIG);
  int r  = idx % (CC * KBIG);
  int c  = r / KBIG;
  int jp = r % KBIG;
  int k = jp >> 7, j = jp & 127;
  float v = loadf(W, ((size_t)(i * NSPL + k) * CC + j) * CC + c, bf);
  ushort_t hi = f2b(v);
  Whi[idx] = hi;
  Wlo[idx] = f2b(v - b2f(hi));
}
// Wsm blocks: b<3 -> root[b][j][c]; b==3 -> finW[c][j]. [4][128][128] hi/lo.
__global__ void prep_wsmall(const void* __restrict__ root, const void* __restrict__ finW,
                            const int* __restrict__ flag,
                            ushort_t* __restrict__ Whi, ushort_t* __restrict__ Wlo) {
  int idx = blockIdx.x * blockDim.x + threadIdx.x;
  if (idx >= 4 * CC * CC) return;
  int bf = *flag;
  int b = idx / (CC * CC);
  int cj = idx % (CC * CC);
  int c = cj >> 7, j = cj & 127;
  float v = (b < 3) ? loadf(root, ((size_t)b * CC + j) * CC + c, bf)
                    : loadf(finW, (size_t)c * CC + j, bf);
  ushort_t hi = f2b(v);
  Whi[idx] = hi;
  Wlo[idx] = f2b(v - b2f(hi));
}

// ---------------- h0 = emb[x] -> h2 (hi|lo per row) ----------------
__global__ void init_h(const int* __restrict__ x, const void* __restrict__ emb,
                       const int* __restrict__ flag, ushort_t* __restrict__ h2) {
  int idx = blockIdx.x * blockDim.x + threadIdx.x;   // over NPAD*128
  int c = idx & 127, n = idx >> 7;
  if (n >= NPAD) return;
  float v = (n < NN) ? loadf(emb, (size_t)x[n] * CC + c, *flag) : 0.0f;
  ushort_t hi = f2b(v);
  h2[(size_t)n * 256 + c]       = hi;
  h2[(size_t)n * 256 + 128 + c] = f2b(v - b2f(hi));
}

// ---------------- CSR build ----------------
__global__ void ideg_kernel(const int* __restrict__ ei, int* __restrict__ ideg, int E) {
  int e = blockIdx.x * blockDim.x + threadIdx.x;
  if (e < E) atomicAdd(&ideg[ei[E + e]], 1);
}
__global__ void rdeg_kernel(const int* __restrict__ ideg, float* __restrict__ deg,
                            float* __restrict__ rdeg) {
  int n = blockIdx.x * blockDim.x + threadIdx.x;
  if (n >= NPAD) return;
  float d = (n < NN) ? (float)ideg[n] : 0.0f;
  deg[n] = d;
  rdeg[n] = 1.0f / fmaxf(d, 1.0f);
}
// single-block exclusive scan: offs[0]=0, offs[n+1]=sum(ideg[0..n])
__global__ void scan_offs(const int* __restrict__ ideg, int* __restrict__ offs) {
  __shared__ int buf[1024];
  __shared__ int carry;
  int tid = threadIdx.x;
  if (tid == 0) { carry = 0; offs[0] = 0; }
  __syncthreads();
  for (int base = 0; base < NN; base += 1024) {
    int v = (base + tid < NN) ? ideg[base + tid] : 0;
    buf[tid] = v;
    __syncthreads();
    for (int s = 1; s < 1024; s <<= 1) {
      int t = (tid >= s) ? buf[tid - s] : 0;
      __syncthreads();
      buf[tid] += t;
      __syncthreads();
    }
    if (base + tid < NN) offs[base + tid + 1] = carry + buf[tid];
    __syncthreads();
    if (tid == 0) carry += buf[1023];
    __syncthreads();
  }
}
// fill: esrc = src | (base<<17); ewt = 4 fp16 weights {w00,w10,w01,w11}
__global__ void fill_csr(const int* __restrict__ ei, const void* __restrict__ eattr,
                         const int* __restrict__ flag, const int* __restrict__ offs,
                         int* __restrict__ cursor, uint32_t* __restrict__ esrc,
                         uint2* __restrict__ ewt, int E) {
  int e = blockIdx.x * blockDim.x + threadIdx.x;
  if (e >= E) return;
  int bf = *flag;
  int src = ei[e], dst = ei[E + e];
  float a0, a1;
  if (bf) {
    uint32_t ap = ((const uint32_t*)eattr)[e];
    a0 = b2f(ap & 0xffffu); a1 = b2f(ap >> 16);
  } else {
    float2 f = ((const float2*)eattr)[e];
    a0 = f.x; a1 = f.y;
  }
  float v0 = fminf(fmaxf(a0 * 4.0f, 0.0f), 4.0f);
  float v1 = fminf(fmaxf(a1 * 4.0f, 0.0f), 4.0f);
  float lo0 = fminf(floorf(v0), 3.0f);
  float lo1 = fminf(floorf(v1), 3.0f);
  float f0 = v0 - lo0, f1 = v1 - lo1;
  int base = (int)lo0 + 5 * (int)lo1;
  int pos = atomicAdd(&cursor[dst], 1);
  int slot = offs[dst] + pos;
  esrc[slot] = (uint32_t)src | ((uint32_t)base << 17);
  union { _Float16 h[2]; uint32_t u; } p0, p1;
  p0.h[0] = (_Float16)((1.0f - f0) * (1.0f - f1));
  p0.h[1] = (_Float16)(f0 * (1.0f - f1));
  p1.h[0] = (_Float16)((1.0f - f0) * f1);
  p1.h[1] = (_Float16)(f0 * f1);
  ewt[slot] = make_uint2(p0.u, p1.u);
}

// ---------------- edge pass: U[n][k][c] = sum_{e->n} w_k(e) * h_hi[src_e][c] ----------------
// One wave per node; private LDS tile 25*128 fp32, bank-permuted: channel c stored at
// slot pos (c>>1) + (c&1)*64  -> lane l handles c=2l,2l+1 via two stride-64 b32 ops (2-way, free).
__global__ __launch_bounds__(256) void edge_u(
    const int* __restrict__ offs, const uint32_t* __restrict__ esrc,
    const uint2* __restrict__ ewt, const ushort_t* __restrict__ h2,
    ushort_t* __restrict__ U, int n0, int n1) {
  __shared__ float ulds[4][3200];
  const int w = threadIdx.x >> 6, l = threadIdx.x & 63;
  float* up = &ulds[w][0];
  for (int n = n0 + blockIdx.x * 4 + w; n < n1; n += gridDim.x * 4) {
    for (int i = l; i < 3200; i += 64) up[i] = 0.0f;
    int o0 = offs[n], o1 = offs[n + 1];
    for (int o = o0; o < o1; ++o) {
      uint32_t sp = esrc[o];
      int src = sp & 0x1ffff, base = sp >> 17;
      uint2 wp = ewt[o];
      uint32_t hw = *(const uint32_t*)(h2 + (size_t)src * 256 + 2 * l);
      float h0 = b2f(hw & 0xffffu), h1 = b2f(hw >> 16);
      union { uint32_t u; _Float16 h[2]; } c0, c1;
      c0.u = wp.x; c1.u = wp.y;
      float wv[4] = {(float)c0.h[0], (float)c0.h[1], (float)c1.h[0], (float)c1.h[1]};
      const int koff[4] = {0, 1, 5, 6};
#pragma unroll
      for (int t = 0; t < 4; ++t) {
        int kb = (base + koff[t]) << 7;
        up[kb + l]      += wv[t] * h0;
        up[kb + 64 + l] += wv[t] * h1;
      }
    }
    ushort_t* Ur = U + (size_t)(n - n0) * KBIG;
    for (int i = l; i < 1600; i += 64) {
      int k = i >> 6, r = i & 63;
      float u0 = up[(k << 7) + r];
      float u1 = up[(k << 7) + 64 + r];
      ((uint32_t*)Ur)[i] = (uint32_t)f2b(u0) | ((uint32_t)f2b(u1) << 16);
    }
  }
}

// ---------------- U GEMM: agg[n0+m][c] += sum_{j'} U[m][j'] * (Whi+Wlo)[c][j'] ----------------
__global__ __launch_bounds__(256, 2) void gemm_u(
    const ushort_t* __restrict__ U, const ushort_t* __restrict__ Bhi,
    const ushort_t* __restrict__ Blo, float* __restrict__ agg,
    int n0, int mvalid) {
  __shared__ char sm[65536];
  char* smA = sm;
  char* smB = sm + 32768;
  const int m0 = blockIdx.x * 128;
  const int tid = threadIdx.x;
  const int w = tid >> 6, l = tid & 63;
  const int lr = l & 15, lg = l >> 4;
  const int wr = w >> 1, wc = w & 1;

  f32x4 acc[4][4] = {};
  for (int pass = 0; pass < 2; ++pass) {
    const ushort_t* Bp = pass ? Blo : Bhi;
    for (int kc = 0; kc < NSPL; ++kc) {
      for (int i = 0; i < 8; ++i) {
        int row    = w * 32 + i * 4 + lg;
        int gchunk = lr ^ (row & 7);
        const ushort_t* gA = U + (size_t)(m0 + row) * KBIG + kc * 128 + gchunk * 8;
        const ushort_t* gB = Bp + (size_t)row * KBIG + kc * 128 + gchunk * 8;
        __builtin_amdgcn_global_load_lds(
            (const __attribute__((address_space(1))) void*)gA,
            (__attribute__((address_space(3))) void*)(smA + (w * 32 + i * 4) * 256), 16, 0, 0);
        __builtin_amdgcn_global_load_lds(
            (const __attribute__((address_space(1))) void*)gB,
            (__attribute__((address_space(3))) void*)(smB + (w * 32 + i * 4) * 256), 16, 0, 0);
      }
      __syncthreads();
      for (int kk = 0; kk < 4; ++kk) {
        bf16x8 av[4], bv[4];
#pragma unroll
        for (int mi = 0; mi < 4; ++mi) {
          int row   = wr * 64 + mi * 16 + lr;
          int chunk = (kk * 4 + lg) ^ (row & 7);
          av[mi] = *(const bf16x8*)(smA + row * 256 + chunk * 16);
        }
#pragma unroll
        for (int ni = 0; ni < 4; ++ni) {
          int row   = wc * 64 + ni * 16 + lr;
          int chunk = (kk * 4 + lg) ^ (row & 7);
          bv[ni] = *(const bf16x8*)(smB + row * 256 + chunk * 16);
        }
#pragma unroll
        for (int mi = 0; mi < 4; ++mi)
#pragma unroll
          for (int ni = 0; ni < 4; ++ni)
            acc[mi][ni] = __builtin_amdgcn_mfma_f32_16x16x32_bf16(av[mi], bv[ni], acc[mi][ni], 0, 0, 0);
      }
      __syncthreads();
    }
  }
  // C/D layout: col = lane&15, row = (lane>>4)*4 + j
  const int colb = wc * 64;
#pragma unroll
  for (int mi = 0; mi < 4; ++mi) {
    int growbase = m0 + wr * 64 + mi * 16 + lg * 4;
#pragma unroll
    for (int ni = 0; ni < 4; ++ni) {
      int col = colb + ni * 16 + lr;
      f32x4 v = acc[mi][ni];
#pragma unroll
      for (int j = 0; j < 4; ++j) {
        int grow = growbase + j;
        if (grow < mvalid) {
          float* ag = agg + (size_t)(n0 + grow) * CC + col;
          *ag += v[j];
        }
      }
    }
  }
}

// ---------------- small-K GEMM over h2 (3-chunk split precision) ----------------
// MODE 1: final -> d_out (dtype by flag) + bias. MODE 2: agg = acc * max(deg,1).
template <int MODE>
__global__ __launch_bounds__(256, 2) void gemm_split(
    const ushort_t* __restrict__ A2,
    const ushort_t* __restrict__ Bhi, const ushort_t* __restrict__ Blo,
    const void* __restrict__ bias, const int* __restrict__ flag,
    const float* __restrict__ deg,
    void* __restrict__ Cout, int ldc, int Mvalid) {
  __shared__ char sm[65536];
  char* smA = sm;
  char* smB = sm + 32768;
  const int m0 = blockIdx.x * 128;
  const int tid = threadIdx.x;
  const int w = tid >> 6, l = tid & 63;
  const int lr = l & 15, lg = l >> 4;
  const int wr = w >> 1, wc = w & 1;

  f32x4 acc[4][4] = {};
#pragma unroll
  for (int ch = 0; ch < 3; ++ch) {
    const ushort_t* Ab = A2 + (ch == 1 ? 128 : 0);
    const ushort_t* Bb = (ch == 2 ? Blo : Bhi);
    for (int i = 0; i < 8; ++i) {
      int row    = w * 32 + i * 4 + lg;
      int gchunk = lr ^ (row & 7);
      const ushort_t* gA = Ab + (size_t)(m0 + row) * 256 + gchunk * 8;
      const ushort_t* gB = Bb + (size_t)row * CC + gchunk * 8;
      __builtin_amdgcn_global_load_lds(
          (const __attribute__((address_space(1))) void*)gA,
          (__attribute__((address_space(3))) void*)(smA + (w * 32 + i * 4) * 256), 16, 0, 0);
      __builtin_amdgcn_global_load_lds(
          (const __attribute__((address_space(1))) void*)gB,
          (__attribute__((address_space(3))) void*)(smB + (w * 32 + i * 4) * 256), 16, 0, 0);
    }
    __syncthreads();
    for (int kk = 0; kk < 4; ++kk) {
      bf16x8 av[4], bv[4];
#pragma unroll
      for (int mi = 0; mi < 4; ++mi) {
        int row   = wr * 64 + mi * 16 + lr;
        int chunk = (kk * 4 + lg) ^ (row & 7);
        av[mi] = *(const bf16x8*)(smA + row * 256 + chunk * 16);
      }
#pragma unroll
      for (int ni = 0; ni < 4; ++ni) {
        int row   = wc * 64 + ni * 16 + lr;
        int chunk = (kk * 4 + lg) ^ (row & 7);
        bv[ni] = *(const bf16x8*)(smB + row * 256 + chunk * 16);
      }
#pragma unroll
      for (int mi = 0; mi < 4; ++mi)
#pragma unroll
        for (int ni = 0; ni < 4; ++ni)
          acc[mi][ni] = __builtin_amdgcn_mfma_f32_16x16x32_bf16(av[mi], bv[ni], acc[mi][ni], 0, 0, 0);
    }
    __syncthreads();
  }
  const int bf = (MODE == 1) ? *flag : 0;
  const int colb = wc * 64;
#pragma unroll
  for (int mi = 0; mi < 4; ++mi) {
    int growbase = m0 + wr * 64 + mi * 16 + lg * 4;
#pragma unroll
    for (int ni = 0; ni < 4; ++ni) {
      int col = colb + ni * 16 + lr;
      float badd = (MODE == 1) ? loadf(bias, col, bf) : 0.0f;
      f32x4 v = acc[mi][ni];
#pragma unroll
      for (int j = 0; j < 4; ++j) {
        int grow = growbase + j;
        if (grow < Mvalid) {
          if (MODE == 2) {
            float dscale = fmaxf(deg[grow], 1.0f);
            ((float*)Cout)[(size_t)grow * ldc + col] = v[j] * dscale;
          } else {
            float val = v[j] + badd;
            if (bf) ((ushort_t*)Cout)[(size_t)grow * ldc + col] = f2b(val);
            else    ((float*)Cout)[(size_t)grow * ldc + col] = val;
          }
        }
      }
    }
  }
}

// ---------------- node: y = agg*rdeg + bias ; BN partial sums ----------------
__global__ __launch_bounds__(256) void node_bn(
    float* __restrict__ agg, const float* __restrict__ rdeg,
    const void* __restrict__ bias, int layer, const int* __restrict__ flag,
    float* __restrict__ bnsum, float* __restrict__ bnsq) {
  int c   = threadIdx.x & 127;
  int sub = threadIdx.x >> 7;
  float b = loadf(bias, (size_t)layer * CC + c, *flag);
  float lsum = 0.0f, lsq = 0.0f;
  for (int n = blockIdx.x * 2 + sub; n < NN; n += gridDim.x * 2) {
    float y = agg[(size_t)n * CC + c] * rdeg[n] + b;
    agg[(size_t)n * CC + c] = y;
    lsum += y; lsq += y * y;
  }
  __shared__ float ssum[256], ssq[256];
  ssum[threadIdx.x] = lsum; ssq[threadIdx.x] = lsq;
  __syncthreads();
  if (sub == 0) {
    unsafeAtomicAdd(&bnsum[c], ssum[c] + ssum[c + 128]);
    unsafeAtomicAdd(&bnsq[c],  ssq[c]  + ssq[c + 128]);
  }
}

__global__ void bn_final(const float* __restrict__ bnsum, const float* __restrict__ bnsq,
                         const void* __restrict__ gamma, const void* __restrict__ beta,
                         int layer, const int* __restrict__ flag,
                         float* __restrict__ scale, float* __restrict__ shift) {
  int c = threadIdx.x;
  int bf = *flag;
  float mean = bnsum[c] * (1.0f / NN);
  float var  = fmaxf(bnsq[c] * (1.0f / NN) - mean * mean, 0.0f);
  float sc = loadf(gamma, (size_t)layer * CC + c, bf) * rsqrtf(var + 1e-5f);
  scale[c] = sc;
  shift[c] = loadf(beta, (size_t)layer * CC + c, bf) - mean * sc;
}

template <bool RELU>
__global__ void norm_kernel(const float* __restrict__ y, const float* __restrict__ scale,
                            const float* __restrict__ shift, ushort_t* __restrict__ h2) {
  int idx = blockIdx.x * blockDim.x + threadIdx.x;   // over NPAD*128
  int c = idx & 127, n = idx >> 7;
  if (n >= NPAD) return;
  float v = 0.0f;
  if (n < NN) {
    v = scale[c] * y[idx] + shift[c];
    if (RELU) v = fmaxf(v, 0.0f);
  }
  ushort_t hi = f2b(v);
  h2[(size_t)n * 256 + c]       = hi;
  h2[(size_t)n * 256 + 128 + c] = f2b(v - b2f(hi));
}

// ---------------- launch ----------------
extern "C" void kernel_launch(void* const* d_in, const int* in_sizes, int n_in,
                              void* d_out, int out_size, void* d_ws, size_t ws_size,
                              hipStream_t stream) {
  const int*  x     = (const int*)d_in[0];
  const int*  ei    = (const int*)d_in[1];
  const void* eattr = d_in[2];
  const void* emb   = d_in[3];
  const void* convW = d_in[4];
  const void* convR = d_in[5];
  const void* convB = d_in[6];
  const void* gamma = d_in[7];
  const void* beta  = d_in[8];
  const void* finW  = d_in[9];
  const void* finB  = d_in[10];
  const int E = in_sizes[1] / 2;

  char* ws = (char*)d_ws;
  size_t off = 0;
  auto alloc = [&](size_t bytes) -> char* {
    char* p = ws + off; off += (bytes + 255) & ~(size_t)255; return p;
  };
  int*      flag   = (int*)alloc(256);
  ushort_t* WcatHi = (ushort_t*)alloc((size_t)LAYERS * CC * KBIG * 2);   // 2.46 MB
  ushort_t* WcatLo = (ushort_t*)alloc((size_t)LAYERS * CC * KBIG * 2);
  ushort_t* WsmHi  = (ushort_t*)alloc((size_t)4 * CC * CC * 2);          // 128 KB
  ushort_t* WsmLo  = (ushort_t*)alloc((size_t)4 * CC * CC * 2);
  ushort_t* h2     = (ushort_t*)alloc((size_t)NPAD * 256 * 2);           // 25.6 MB
  float*    agg    = (float*)alloc((size_t)NPAD * CC * 4);               // 25.6 MB
  int*      ideg   = (int*)alloc((size_t)NPAD * 4);
  float*    deg    = (float*)alloc((size_t)NPAD * 4);
  float*    rdeg   = (float*)alloc((size_t)NPAD * 4);
  int*      offs   = (int*)alloc((size_t)(NN + 1) * 4);
  int*      cursor = (int*)alloc((size_t)NN * 4);
  uint32_t* esrc   = (uint32_t*)alloc((size_t)E * 4);                    // 6.4 MB
  uint2*    ewt    = (uint2*)alloc((size_t)E * 8);                       // 12.8 MB
  float*    bnst   = (float*)alloc(4 * CC * 4);   // sum | sq | scale | shift

  // U chunk: rows of [KBIG] bf16, adaptive to remaining ws
  size_t avail = (ws_size > off + 4096) ? (ws_size - off - 4096) : 0;
  long rows = (long)(avail / (KBIG * 2));
  rows &= ~127L;
  if (rows < 128) rows = 128;
  if (rows > NPAD) rows = NPAD;
  int nch = (int)((NPAD + rows - 1) / rows);
  rows = (((NPAD + nch - 1) / nch + 127) / 128) * 128;
  while ((long)nch * rows < NPAD) rows += 128;
  ushort_t* U = (ushort_t*)(ws + off);

  probe_dtype<<<1, 64, 0, stream>>>((const uint32_t*)emb, flag);
  hipMemsetAsync(ideg, 0, (size_t)NPAD * 4, stream);
  hipMemsetAsync(cursor, 0, (size_t)NN * 4, stream);
  prep_wcat<<<(LAYERS * CC * KBIG + 255) / 256, 256, 0, stream>>>(convW, flag, WcatHi, WcatLo);
  prep_wsmall<<<(4 * CC * CC + 255) / 256, 256, 0, stream>>>(convR, finW, flag, WsmHi, WsmLo);
  init_h<<<(NPAD * CC) / 256, 256, 0, stream>>>(x, emb, flag, h2);
  ideg_kernel<<<(E + 255) / 256, 256, 0, stream>>>(ei, ideg, E);
  rdeg_kernel<<<(NPAD + 255) / 256, 256, 0, stream>>>(ideg, deg, rdeg);
  scan_offs<<<1, 1024, 0, stream>>>(ideg, offs);
  fill_csr<<<(E + 255) / 256, 256, 0, stream>>>(ei, eattr, flag, offs, cursor, esrc, ewt, E);

  for (int i = 0; i < LAYERS; ++i) {
    hipMemsetAsync(bnst, 0, 2 * CC * 4, stream);
    // root term: agg = (h @ root) * max(deg,1)
    gemm_split<2><<<dim3(MT, 1), 256, 0, stream>>>(
        h2, WsmHi + (size_t)i * CC * CC, WsmLo + (size_t)i * CC * CC,
        nullptr, flag, deg, agg, CC, NPAD);
    for (int ch = 0; ch < nch; ++ch) {
      int n0 = ch * (int)rows;
      int n1 = n0 + (int)rows; if (n1 > NPAD) n1 = NPAD;
      int n1v = n1 < NN ? n1 : NN;
      edge_u<<<(n1v - n0 + 3) / 4, 256, 0, stream>>>(offs, esrc, ewt, h2, U, n0, n1v);
      gemm_u<<<(n1 - n0) / 128, 256, 0, stream>>>(
          U, WcatHi + (size_t)i * CC * KBIG, WcatLo + (size_t)i * CC * KBIG,
          agg, n0, NN - n0);
    }
    node_bn<<<1024, 256, 0, stream>>>(agg, rdeg, convB, i, flag, bnst, bnst + 128);
    bn_final<<<1, 128, 0, stream>>>(bnst, bnst + 128, gamma, beta, i, flag,
                                    bnst + 256, bnst + 384);
    if (i < LAYERS - 1)
      norm_kernel<true><<<(NPAD * CC) / 256, 256, 0, stream>>>(agg, bnst + 256, bnst + 384, h2);
    else
      norm_kernel<false><<<(NPAD * CC) / 256, 256, 0, stream>>>(agg, bnst + 256, bnst + 384, h2);
  }
  gemm_split<1><<<dim3(MT, 1), 256, 0, stream>>>(
      h2, WsmHi + (size_t)3 * CC * CC, WsmLo + (size_t)3 * CC * CC,
      finB, flag, deg, d_out, CC, NN);
}

// Round 6
// 1454.733 us; speedup vs baseline: 4.4032x; 1.7718x over previous
//
#include <hip/hip_runtime.h>
#include <hip/hip_bf16.h>
#include <stdint.h>

// ---------------- problem constants ----------------
#define NN      50000          // nodes
#define NPAD    50048          // 391 * 128
#define MT      391            // M tiles of 128
#define CC      128            // channels
#define NSPL    25             // spline kernel slots
#define KBIG    3200           // 25 * 128 contraction for U GEMM
#define LAYERS  3

typedef unsigned short ushort_t;
typedef __attribute__((ext_vector_type(8))) short bf16x8;
typedef _Float16 f16x8 __attribute__((ext_vector_type(8)));
typedef __attribute__((ext_vector_type(4))) float f32x4;

__device__ __forceinline__ float b2f(uint32_t hi16) {
  union { uint32_t u; float f; } v; v.u = hi16 << 16; return v.f;
}
__device__ __forceinline__ ushort_t f2b(float f) {
  union { float f; uint32_t u; } v; v.f = f;
  uint32_t u = v.u;
  return (ushort_t)((u + 0x7fffu + ((u >> 16) & 1u)) >> 16);
}
__device__ __forceinline__ ushort_t f2h(float f) {
  union { _Float16 h[2]; uint32_t u; } v; v.h[0] = (_Float16)f; v.h[1] = (_Float16)0.0f;
  return (ushort_t)(v.u & 0xffffu);
}
__device__ __forceinline__ float loadf(const void* p, size_t i, int bf) {
  return bf ? b2f(((const ushort_t*)p)[i]) : ((const float*)p)[i];
}

// ---------------- dtype probe (bf16 vs fp32 inputs) ----------------
__global__ void probe_dtype(const uint32_t* __restrict__ emb_w, int* __restrict__ flag) {
  int l = threadIdx.x;
  uint32_t w = emb_w[l];
  int e = (w >> 7) & 0xff;
  int hit = (e >= 118 && e <= 134) ? 1 : 0;
  unsigned long long m = __ballot(hit);
  if (l == 0) *flag = (__popcll(m) >= 48) ? 1 : 0;
}

// ---------------- weight prep ----------------
// Wcat16[i][c][k*128+j] = fp16(W[i][k][j][c]). [LAYERS][128][3200]
__global__ void prep_wcat(const void* __restrict__ W, const int* __restrict__ flag,
                          ushort_t* __restrict__ W16) {
  int idx = blockIdx.x * blockDim.x + threadIdx.x;
  const int total = LAYERS * CC * KBIG;
  if (idx >= total) return;
  int bf = *flag;
  int i  = idx / (CC * KBIG);
  int r  = idx % (CC * KBIG);
  int c  = r / KBIG;
  int jp = r % KBIG;
  int k = jp >> 7, j = jp & 127;
  float v = loadf(W, ((size_t)(i * NSPL + k) * CC + j) * CC + c, bf);
  W16[idx] = f2h(v);
}
// Wsm blocks: b<3 -> root[b][j][c]; b==3 -> finW[c][j]. [4][128][128] hi/lo bf16.
__global__ void prep_wsmall(const void* __restrict__ root, const void* __restrict__ finW,
                            const int* __restrict__ flag,
                            ushort_t* __restrict__ Whi, ushort_t* __restrict__ Wlo) {
  int idx = blockIdx.x * blockDim.x + threadIdx.x;
  if (idx >= 4 * CC * CC) return;
  int bf = *flag;
  int b = idx / (CC * CC);
  int cj = idx % (CC * CC);
  int c = cj >> 7, j = cj & 127;
  float v = (b < 3) ? loadf(root, ((size_t)b * CC + j) * CC + c, bf)
                    : loadf(finW, (size_t)c * CC + j, bf);
  ushort_t hi = f2b(v);
  Whi[idx] = hi;
  Wlo[idx] = f2b(v - b2f(hi));
}

// ---------------- h0 = emb[x] -> h2 (bf16 hi|lo) + h16 (fp16) ----------------
__global__ void init_h(const int* __restrict__ x, const void* __restrict__ emb,
                       const int* __restrict__ flag, ushort_t* __restrict__ h2,
                       ushort_t* __restrict__ h16) {
  int idx = blockIdx.x * blockDim.x + threadIdx.x;   // over NPAD*128
  int c = idx & 127, n = idx >> 7;
  if (n >= NPAD) return;
  float v = (n < NN) ? loadf(emb, (size_t)x[n] * CC + c, *flag) : 0.0f;
  ushort_t hi = f2b(v);
  h2[(size_t)n * 256 + c]       = hi;
  h2[(size_t)n * 256 + 128 + c] = f2b(v - b2f(hi));
  h16[idx] = f2h(v);
}

// ---------------- CSR build ----------------
__global__ void ideg_kernel(const int* __restrict__ ei, int* __restrict__ ideg, int E) {
  int e = blockIdx.x * blockDim.x + threadIdx.x;
  if (e < E) atomicAdd(&ideg[ei[E + e]], 1);
}
__global__ void rdeg_kernel(const int* __restrict__ ideg, float* __restrict__ deg,
                            float* __restrict__ rdeg) {
  int n = blockIdx.x * blockDim.x + threadIdx.x;
  if (n >= NPAD) return;
  float d = (n < NN) ? (float)ideg[n] : 0.0f;
  deg[n] = d;
  rdeg[n] = 1.0f / fmaxf(d, 1.0f);
}
// single-block exclusive scan, 4 elems/thread
__global__ void scan_offs(const int* __restrict__ ideg, int* __restrict__ offs) {
  __shared__ int buf[1024];
  __shared__ int carry;
  int tid = threadIdx.x;
  if (tid == 0) { carry = 0; offs[0] = 0; }
  __syncthreads();
  for (int base = 0; base < NN; base += 4096) {
    int i0 = base + tid * 4;
    int v0 = (i0 + 0 < NN) ? ideg[i0 + 0] : 0;
    int v1 = (i0 + 1 < NN) ? ideg[i0 + 1] : 0;
    int v2 = (i0 + 2 < NN) ? ideg[i0 + 2] : 0;
    int v3 = (i0 + 3 < NN) ? ideg[i0 + 3] : 0;
    int s = v0 + v1 + v2 + v3;
    buf[tid] = s;
    __syncthreads();
    for (int st = 1; st < 1024; st <<= 1) {
      int t = (tid >= st) ? buf[tid - st] : 0;
      __syncthreads();
      buf[tid] += t;
      __syncthreads();
    }
    int pre = carry + buf[tid] - s;
    if (i0 + 0 < NN) offs[i0 + 1] = pre + v0;
    if (i0 + 1 < NN) offs[i0 + 2] = pre + v0 + v1;
    if (i0 + 2 < NN) offs[i0 + 3] = pre + v0 + v1 + v2;
    if (i0 + 3 < NN) offs[i0 + 4] = pre + s;
    __syncthreads();
    if (tid == 0) carry += buf[1023];
    __syncthreads();
  }
}
// fill: esrc = src | (base<<17); ewt = 4 fp16 weights {w00,w10}|{w01,w11}
__global__ void fill_csr(const int* __restrict__ ei, const void* __restrict__ eattr,
                         const int* __restrict__ flag, const int* __restrict__ offs,
                         int* __restrict__ cursor, uint32_t* __restrict__ esrc,
                         uint2* __restrict__ ewt, int E) {
  int e = blockIdx.x * blockDim.x + threadIdx.x;
  if (e >= E) return;
  int bf = *flag;
  int src = ei[e], dst = ei[E + e];
  float a0, a1;
  if (bf) {
    uint32_t ap = ((const uint32_t*)eattr)[e];
    a0 = b2f(ap & 0xffffu); a1 = b2f(ap >> 16);
  } else {
    float2 f = ((const float2*)eattr)[e];
    a0 = f.x; a1 = f.y;
  }
  float v0 = fminf(fmaxf(a0 * 4.0f, 0.0f), 4.0f);
  float v1 = fminf(fmaxf(a1 * 4.0f, 0.0f), 4.0f);
  float lo0 = fminf(floorf(v0), 3.0f);
  float lo1 = fminf(floorf(v1), 3.0f);
  float f0 = v0 - lo0, f1 = v1 - lo1;
  int base = (int)lo0 + 5 * (int)lo1;
  int pos = atomicAdd(&cursor[dst], 1);
  int slot = offs[dst] + pos;
  esrc[slot] = (uint32_t)src | ((uint32_t)base << 17);
  union { _Float16 h[2]; uint32_t u; } p0, p1;
  p0.h[0] = (_Float16)((1.0f - f0) * (1.0f - f1));
  p0.h[1] = (_Float16)(f0 * (1.0f - f1));
  p1.h[0] = (_Float16)((1.0f - f0) * f1);
  p1.h[1] = (_Float16)(f0 * f1);
  ewt[slot] = make_uint2(p0.u, p1.u);
}

// ---------------- edge pass: U[n][k][c] = sum_{e->n} w_k(e) * h16[src_e][c] ----------------
// One wave per node; LDS tile [25][128] fp32, lane l owns channels 2l,2l+1 (b64 RMW).
__device__ __forceinline__ void edge_tap(float* up, int l, uint32_t sp,
                                         uint32_t wx, uint32_t wy, uint32_t hw) {
  int base = (int)(sp >> 17);
  union { uint32_t u; _Float16 h[2]; } cw0, cw1, chh;
  cw0.u = wx; cw1.u = wy; chh.u = hw;
  float h0 = (float)chh.h[0], h1 = (float)chh.h[1];
  float wv0 = (float)cw0.h[0], wv1 = (float)cw0.h[1];
  float wv2 = (float)cw1.h[0], wv3 = (float)cw1.h[1];
  float2* p; float2 v;
  p = (float2*)(up + ((base + 0) << 7) + 2 * l);
  v = *p; v.x += wv0 * h0; v.y += wv0 * h1; *p = v;
  p = (float2*)(up + ((base + 1) << 7) + 2 * l);
  v = *p; v.x += wv1 * h0; v.y += wv1 * h1; *p = v;
  p = (float2*)(up + ((base + 5) << 7) + 2 * l);
  v = *p; v.x += wv2 * h0; v.y += wv2 * h1; *p = v;
  p = (float2*)(up + ((base + 6) << 7) + 2 * l);
  v = *p; v.x += wv3 * h0; v.y += wv3 * h1; *p = v;
}

__global__ __launch_bounds__(256) void edge_u(
    const int* __restrict__ offs, const uint32_t* __restrict__ esrc,
    const uint2* __restrict__ ewt, const ushort_t* __restrict__ h16,
    ushort_t* __restrict__ U, int n0, int n1) {
  __shared__ float ulds[4][3200];
  const int w = threadIdx.x >> 6, l = threadIdx.x & 63;
  float* up = &ulds[w][0];
  for (int n = n0 + blockIdx.x * 4 + w; n < n1; n += gridDim.x * 4) {
#pragma unroll
    for (int k = 0; k < NSPL; ++k)
      *(float2*)(up + (k << 7) + 2 * l) = make_float2(0.0f, 0.0f);
    int o0 = offs[n], o1 = offs[n + 1];
    int o = o0;
    for (; o < o1 && (o & 3); ++o) {
      uint32_t sp = esrc[o];
      uint2 wp = ewt[o];
      uint32_t hw = *(const uint32_t*)(h16 + (size_t)(sp & 0x1ffff) * CC + 2 * l);
      edge_tap(up, l, sp, wp.x, wp.y, hw);
    }
    for (; o + 4 <= o1; o += 4) {
      uint4 sp4 = *(const uint4*)(esrc + o);
      uint4 wa  = *(const uint4*)(ewt + o);
      uint4 wb  = *(const uint4*)(ewt + o + 2);
      uint32_t hw0 = *(const uint32_t*)(h16 + (size_t)(sp4.x & 0x1ffff) * CC + 2 * l);
      uint32_t hw1 = *(const uint32_t*)(h16 + (size_t)(sp4.y & 0x1ffff) * CC + 2 * l);
      uint32_t hw2 = *(const uint32_t*)(h16 + (size_t)(sp4.z & 0x1ffff) * CC + 2 * l);
      uint32_t hw3 = *(const uint32_t*)(h16 + (size_t)(sp4.w & 0x1ffff) * CC + 2 * l);
      edge_tap(up, l, sp4.x, wa.x, wa.y, hw0);
      edge_tap(up, l, sp4.y, wa.z, wa.w, hw1);
      edge_tap(up, l, sp4.z, wb.x, wb.y, hw2);
      edge_tap(up, l, sp4.w, wb.z, wb.w, hw3);
    }
    for (; o < o1; ++o) {
      uint32_t sp = esrc[o];
      uint2 wp = ewt[o];
      uint32_t hw = *(const uint32_t*)(h16 + (size_t)(sp & 0x1ffff) * CC + 2 * l);
      edge_tap(up, l, sp, wp.x, wp.y, hw);
    }
    uint32_t* Ur = (uint32_t*)(U + (size_t)(n - n0) * KBIG);
#pragma unroll
    for (int k = 0; k < NSPL; ++k) {
      float2 u = *(float2*)(up + (k << 7) + 2 * l);
      union { _Float16 h[2]; uint32_t u32; } pk;
      pk.h[0] = (_Float16)u.x; pk.h[1] = (_Float16)u.y;
      Ur[(k << 6) + l] = pk.u32;
    }
  }
}

// ---------------- U GEMM (fp16): agg[n0+m][c] += sum_j U[m][j] * W16[c][j] ----------------
// K split across blockIdx.y (slots 0..12 | 13..24); atomic += epilogue.
__global__ __launch_bounds__(256, 2) void gemm_u(
    const ushort_t* __restrict__ U, const ushort_t* __restrict__ B16,
    float* __restrict__ agg, int n0, int mvalid) {
  __shared__ char sm[65536];
  char* smA = sm;
  char* smB = sm + 32768;
  const int m0 = blockIdx.x * 128;
  const int kc0 = blockIdx.y ? 13 : 0;
  const int kc1 = blockIdx.y ? 25 : 13;
  const int tid = threadIdx.x;
  const int w = tid >> 6, l = tid & 63;
  const int lr = l & 15, lg = l >> 4;
  const int wr = w >> 1, wc = w & 1;

  f32x4 acc[4][4] = {};
  for (int kc = kc0; kc < kc1; ++kc) {
    for (int i = 0; i < 8; ++i) {
      int row    = w * 32 + i * 4 + lg;
      int gchunk = lr ^ (row & 7);
      const ushort_t* gA = U + (size_t)(m0 + row) * KBIG + kc * 128 + gchunk * 8;
      const ushort_t* gB = B16 + (size_t)row * KBIG + kc * 128 + gchunk * 8;
      __builtin_amdgcn_global_load_lds(
          (const __attribute__((address_space(1))) void*)gA,
          (__attribute__((address_space(3))) void*)(smA + (w * 32 + i * 4) * 256), 16, 0, 0);
      __builtin_amdgcn_global_load_lds(
          (const __attribute__((address_space(1))) void*)gB,
          (__attribute__((address_space(3))) void*)(smB + (w * 32 + i * 4) * 256), 16, 0, 0);
    }
    __syncthreads();
    for (int kk = 0; kk < 4; ++kk) {
      f16x8 av[4], bv[4];
#pragma unroll
      for (int mi = 0; mi < 4; ++mi) {
        int row   = wr * 64 + mi * 16 + lr;
        int chunk = (kk * 4 + lg) ^ (row & 7);
        av[mi] = *(const f16x8*)(smA + row * 256 + chunk * 16);
      }
#pragma unroll
      for (int ni = 0; ni < 4; ++ni) {
        int row   = wc * 64 + ni * 16 + lr;
        int chunk = (kk * 4 + lg) ^ (row & 7);
        bv[ni] = *(const f16x8*)(smB + row * 256 + chunk * 16);
      }
#pragma unroll
      for (int mi = 0; mi < 4; ++mi)
#pragma unroll
        for (int ni = 0; ni < 4; ++ni)
          acc[mi][ni] = __builtin_amdgcn_mfma_f32_16x16x32_f16(av[mi], bv[ni], acc[mi][ni], 0, 0, 0);
    }
    __syncthreads();
  }
  const int colb = wc * 64;
#pragma unroll
  for (int mi = 0; mi < 4; ++mi) {
    int growbase = m0 + wr * 64 + mi * 16 + lg * 4;
#pragma unroll
    for (int ni = 0; ni < 4; ++ni) {
      int col = colb + ni * 16 + lr;
      f32x4 v = acc[mi][ni];
#pragma unroll
      for (int j = 0; j < 4; ++j) {
        int grow = growbase + j;
        if (grow < mvalid)
          unsafeAtomicAdd(agg + (size_t)(n0 + grow) * CC + col, v[j]);
      }
    }
  }
}

// ---------------- small-K GEMM over h2 (3-chunk bf16 split precision) ----------------
// MODE 1: final -> d_out (dtype by flag) + bias. MODE 2: agg = acc * max(deg,1).
template <int MODE>
__global__ __launch_bounds__(256, 2) void gemm_split(
    const ushort_t* __restrict__ A2,
    const ushort_t* __restrict__ Bhi, const ushort_t* __restrict__ Blo,
    const void* __restrict__ bias, const int* __restrict__ flag,
    const float* __restrict__ deg,
    void* __restrict__ Cout, int ldc, int Mvalid) {
  __shared__ char sm[65536];
  char* smA = sm;
  char* smB = sm + 32768;
  const int m0 = blockIdx.x * 128;
  const int tid = threadIdx.x;
  const int w = tid >> 6, l = tid & 63;
  const int lr = l & 15, lg = l >> 4;
  const int wr = w >> 1, wc = w & 1;

  f32x4 acc[4][4] = {};
#pragma unroll
  for (int ch = 0; ch < 3; ++ch) {
    const ushort_t* Ab = A2 + (ch == 1 ? 128 : 0);
    const ushort_t* Bb = (ch == 2 ? Blo : Bhi);
    for (int i = 0; i < 8; ++i) {
      int row    = w * 32 + i * 4 + lg;
      int gchunk = lr ^ (row & 7);
      const ushort_t* gA = Ab + (size_t)(m0 + row) * 256 + gchunk * 8;
      const ushort_t* gB = Bb + (size_t)row * CC + gchunk * 8;
      __builtin_amdgcn_global_load_lds(
          (const __attribute__((address_space(1))) void*)gA,
          (__attribute__((address_space(3))) void*)(smA + (w * 32 + i * 4) * 256), 16, 0, 0);
      __builtin_amdgcn_global_load_lds(
          (const __attribute__((address_space(1))) void*)gB,
          (__attribute__((address_space(3))) void*)(smB + (w * 32 + i * 4) * 256), 16, 0, 0);
    }
    __syncthreads();
    for (int kk = 0; kk < 4; ++kk) {
      bf16x8 av[4], bv[4];
#pragma unroll
      for (int mi = 0; mi < 4; ++mi) {
        int row   = wr * 64 + mi * 16 + lr;
        int chunk = (kk * 4 + lg) ^ (row & 7);
        av[mi] = *(const bf16x8*)(smA + row * 256 + chunk * 16);
      }
#pragma unroll
      for (int ni = 0; ni < 4; ++ni) {
        int row   = wc * 64 + ni * 16 + lr;
        int chunk = (kk * 4 + lg) ^ (row & 7);
        bv[ni] = *(const bf16x8*)(smB + row * 256 + chunk * 16);
      }
#pragma unroll
      for (int mi = 0; mi < 4; ++mi)
#pragma unroll
        for (int ni = 0; ni < 4; ++ni)
          acc[mi][ni] = __builtin_amdgcn_mfma_f32_16x16x32_bf16(av[mi], bv[ni], acc[mi][ni], 0, 0, 0);
    }
    __syncthreads();
  }
  const int bf = (MODE == 1) ? *flag : 0;
  const int colb = wc * 64;
#pragma unroll
  for (int mi = 0; mi < 4; ++mi) {
    int growbase = m0 + wr * 64 + mi * 16 + lg * 4;
#pragma unroll
    for (int ni = 0; ni < 4; ++ni) {
      int col = colb + ni * 16 + lr;
      float badd = (MODE == 1) ? loadf(bias, col, bf) : 0.0f;
      f32x4 v = acc[mi][ni];
#pragma unroll
      for (int j = 0; j < 4; ++j) {
        int grow = growbase + j;
        if (grow < Mvalid) {
          if (MODE == 2) {
            float dscale = fmaxf(deg[grow], 1.0f);
            ((float*)Cout)[(size_t)grow * ldc + col] = v[j] * dscale;
          } else {
            float val = v[j] + badd;
            if (bf) ((ushort_t*)Cout)[(size_t)grow * ldc + col] = f2b(val);
            else    ((float*)Cout)[(size_t)grow * ldc + col] = val;
          }
        }
      }
    }
  }
}

// ---------------- node: y = agg*rdeg + bias ; BN partial sums ----------------
__global__ __launch_bounds__(256) void node_bn(
    float* __restrict__ agg, const float* __restrict__ rdeg,
    const void* __restrict__ bias, int layer, const int* __restrict__ flag,
    float* __restrict__ bnsum, float* __restrict__ bnsq) {
  int c   = threadIdx.x & 127;
  int sub = threadIdx.x >> 7;
  float b = loadf(bias, (size_t)layer * CC + c, *flag);
  float lsum = 0.0f, lsq = 0.0f;
  for (int n = blockIdx.x * 2 + sub; n < NN; n += gridDim.x * 2) {
    float y = agg[(size_t)n * CC + c] * rdeg[n] + b;
    agg[(size_t)n * CC + c] = y;
    lsum += y; lsq += y * y;
  }
  __shared__ float ssum[256], ssq[256];
  ssum[threadIdx.x] = lsum; ssq[threadIdx.x] = lsq;
  __syncthreads();
  if (sub == 0) {
    unsafeAtomicAdd(&bnsum[c], ssum[c] + ssum[c + 128]);
    unsafeAtomicAdd(&bnsq[c],  ssq[c]  + ssq[c + 128]);
  }
}

__global__ void bn_final(const float* __restrict__ bnsum, const float* __restrict__ bnsq,
                         const void* __restrict__ gamma, const void* __restrict__ beta,
                         int layer, const int* __restrict__ flag,
                         float* __restrict__ scale, float* __restrict__ shift) {
  int c = threadIdx.x;
  int bf = *flag;
  float mean = bnsum[c] * (1.0f / NN);
  float var  = fmaxf(bnsq[c] * (1.0f / NN) - mean * mean, 0.0f);
  float sc = loadf(gamma, (size_t)layer * CC + c, bf) * rsqrtf(var + 1e-5f);
  scale[c] = sc;
  shift[c] = loadf(beta, (size_t)layer * CC + c, bf) - mean * sc;
}

template <bool RELU>
__global__ void norm_kernel(const float* __restrict__ y, const float* __restrict__ scale,
                            const float* __restrict__ shift, ushort_t* __restrict__ h2,
                            ushort_t* __restrict__ h16) {
  int idx = blockIdx.x * blockDim.x + threadIdx.x;   // over NPAD*128
  int c = idx & 127, n = idx >> 7;
  if (n >= NPAD) return;
  float v = 0.0f;
  if (n < NN) {
    v = scale[c] * y[idx] + shift[c];
    if (RELU) v = fmaxf(v, 0.0f);
  }
  ushort_t hi = f2b(v);
  h2[(size_t)n * 256 + c]       = hi;
  h2[(size_t)n * 256 + 128 + c] = f2b(v - b2f(hi));
  h16[idx] = f2h(v);
}

// ---------------- launch ----------------
extern "C" void kernel_launch(void* const* d_in, const int* in_sizes, int n_in,
                              void* d_out, int out_size, void* d_ws, size_t ws_size,
                              hipStream_t stream) {
  const int*  x     = (const int*)d_in[0];
  const int*  ei    = (const int*)d_in[1];
  const void* eattr = d_in[2];
  const void* emb   = d_in[3];
  const void* convW = d_in[4];
  const void* convR = d_in[5];
  const void* convB = d_in[6];
  const void* gamma = d_in[7];
  const void* beta  = d_in[8];
  const void* finW  = d_in[9];
  const void* finB  = d_in[10];
  const int E = in_sizes[1] / 2;

  char* ws = (char*)d_ws;
  size_t off = 0;
  auto alloc = [&](size_t bytes) -> char* {
    char* p = ws + off; off += (bytes + 255) & ~(size_t)255; return p;
  };
  int*      flag   = (int*)alloc(256);
  ushort_t* Wcat16 = (ushort_t*)alloc((size_t)LAYERS * CC * KBIG * 2);   // 2.46 MB
  ushort_t* WsmHi  = (ushort_t*)alloc((size_t)4 * CC * CC * 2);          // 128 KB
  ushort_t* WsmLo  = (ushort_t*)alloc((size_t)4 * CC * CC * 2);
  ushort_t* h2     = (ushort_t*)alloc((size_t)NPAD * 256 * 2);           // 25.6 MB
  ushort_t* h16    = (ushort_t*)alloc((size_t)NPAD * CC * 2);            // 12.8 MB
  float*    agg    = (float*)alloc((size_t)NPAD * CC * 4);               // 25.6 MB
  int*      ideg   = (int*)alloc((size_t)NPAD * 4);
  float*    deg    = (float*)alloc((size_t)NPAD * 4);
  float*    rdeg   = (float*)alloc((size_t)NPAD * 4);
  int*      offs   = (int*)alloc((size_t)(NN + 1) * 4);
  int*      cursor = (int*)alloc((size_t)NN * 4);
  uint32_t* esrc   = (uint32_t*)alloc((size_t)E * 4);                    // 6.4 MB
  uint2*    ewt    = (uint2*)alloc((size_t)E * 8);                       // 12.8 MB
  float*    bnst   = (float*)alloc(4 * CC * 4);   // sum | sq | scale | shift

  // U chunk: rows of [KBIG] fp16, adaptive to remaining ws
  size_t avail = (ws_size > off + 4096) ? (ws_size - off - 4096) : 0;
  long rows = (long)(avail / (KBIG * 2));
  rows &= ~127L;
  if (rows < 128) rows = 128;
  if (rows > NPAD) rows = NPAD;
  int nch = (int)((NPAD + rows - 1) / rows);
  rows = (((NPAD + nch - 1) / nch + 127) / 128) * 128;
  while ((long)nch * rows < NPAD) rows += 128;
  ushort_t* U = (ushort_t*)(ws + off);

  probe_dtype<<<1, 64, 0, stream>>>((const uint32_t*)emb, flag);
  hipMemsetAsync(ideg, 0, (size_t)NPAD * 4, stream);
  hipMemsetAsync(cursor, 0, (size_t)NN * 4, stream);
  prep_wcat<<<(LAYERS * CC * KBIG + 255) / 256, 256, 0, stream>>>(convW, flag, Wcat16);
  prep_wsmall<<<(4 * CC * CC + 255) / 256, 256, 0, stream>>>(convR, finW, flag, WsmHi, WsmLo);
  init_h<<<(NPAD * CC) / 256, 256, 0, stream>>>(x, emb, flag, h2, h16);
  ideg_kernel<<<(E + 255) / 256, 256, 0, stream>>>(ei, ideg, E);
  rdeg_kernel<<<(NPAD + 255) / 256, 256, 0, stream>>>(ideg, deg, rdeg);
  scan_offs<<<1, 1024, 0, stream>>>(ideg, offs);
  fill_csr<<<(E + 255) / 256, 256, 0, stream>>>(ei, eattr, flag, offs, cursor, esrc, ewt, E);

  for (int i = 0; i < LAYERS; ++i) {
    hipMemsetAsync(bnst, 0, 2 * CC * 4, stream);
    // root term: agg = (h @ root) * max(deg,1)
    gemm_split<2><<<dim3(MT, 1), 256, 0, stream>>>(
        h2, WsmHi + (size_t)i * CC * CC, WsmLo + (size_t)i * CC * CC,
        nullptr, flag, deg, agg, CC, NPAD);
    for (int ch = 0; ch < nch; ++ch) {
      int n0 = ch * (int)rows;
      int n1 = n0 + (int)rows; if (n1 > NPAD) n1 = NPAD;
      int n1v = n1 < NN ? n1 : NN;
      if (n1v > n0)
        edge_u<<<(n1v - n0 + 3) / 4, 256, 0, stream>>>(offs, esrc, ewt, h16, U, n0, n1v);
      gemm_u<<<dim3((n1 - n0) / 128, 2), 256, 0, stream>>>(
          U, Wcat16 + (size_t)i * CC * KBIG, agg, n0, NN - n0);
    }
    node_bn<<<1024, 256, 0, stream>>>(agg, rdeg, convB, i, flag, bnst, bnst + 128);
    bn_final<<<1, 128, 0, stream>>>(bnst, bnst + 128, gamma, beta, i, flag,
                                    bnst + 256, bnst + 384);
    if (i < LAYERS - 1)
      norm_kernel<true><<<(NPAD * CC) / 256, 256, 0, stream>>>(agg, bnst + 256, bnst + 384, h2, h16);
    else
      norm_kernel<false><<<(NPAD * CC) / 256, 256, 0, stream>>>(agg, bnst + 256, bnst + 384, h2, h16);
  }
  gemm_split<1><<<dim3(MT, 1), 256, 0, stream>>>(
      h2, WsmHi + (size_t)3 * CC * CC, WsmLo + (size_t)3 * CC * CC,
      finB, flag, deg, d_out, CC, NN);
}

// Round 7
// 1262.379 us; speedup vs baseline: 5.0742x; 1.1524x over previous
//
#include <hip/hip_runtime.h>
#include <hip/hip_bf16.h>
#include <stdint.h>

// ---------------- problem constants ----------------
#define NN      50000          // nodes
#define NPAD    50048          // 391 * 128
#define MT      391            // M tiles of 128
#define CC      128            // channels
#define NSPL    25             // spline kernel slots
#define KB3     3328           // 26 * 128 contraction for U GEMM (25 spline + root)
#define LAYERS  3

typedef unsigned short ushort_t;
typedef __attribute__((ext_vector_type(8))) short bf16x8;
typedef _Float16 f16x8 __attribute__((ext_vector_type(8)));
typedef __attribute__((ext_vector_type(4))) float f32x4;

__device__ __forceinline__ float b2f(uint32_t hi16) {
  union { uint32_t u; float f; } v; v.u = hi16 << 16; return v.f;
}
__device__ __forceinline__ ushort_t f2b(float f) {
  union { float f; uint32_t u; } v; v.f = f;
  uint32_t u = v.u;
  return (ushort_t)((u + 0x7fffu + ((u >> 16) & 1u)) >> 16);
}
__device__ __forceinline__ ushort_t f2h(float f) {
  union { _Float16 h[2]; uint32_t u; } v; v.h[0] = (_Float16)f; v.h[1] = (_Float16)0.0f;
  return (ushort_t)(v.u & 0xffffu);
}
__device__ __forceinline__ float loadf(const void* p, size_t i, int bf) {
  return bf ? b2f(((const ushort_t*)p)[i]) : ((const float*)p)[i];
}

// ---------------- dtype probe (bf16 vs fp32 inputs) ----------------
__global__ void probe_dtype(const uint32_t* __restrict__ emb_w, int* __restrict__ flag) {
  int l = threadIdx.x;
  uint32_t w = emb_w[l];
  int e = (w >> 7) & 0xff;
  int hit = (e >= 118 && e <= 134) ? 1 : 0;
  unsigned long long m = __ballot(hit);
  if (l == 0) *flag = (__popcll(m) >= 48) ? 1 : 0;
}

// ---------------- weight prep ----------------
// Wcat16[i][c][k*128+j] = fp16( k<25 ? W[i][k][j][c] : root[i][j][c] ). [LAYERS][128][3328]
__global__ void prep_wcat(const void* __restrict__ W, const void* __restrict__ root,
                          const int* __restrict__ flag, ushort_t* __restrict__ W16) {
  int idx = blockIdx.x * blockDim.x + threadIdx.x;
  const int total = LAYERS * CC * KB3;
  if (idx >= total) return;
  int bf = *flag;
  int i  = idx / (CC * KB3);
  int r  = idx % (CC * KB3);
  int c  = r / KB3;
  int jp = r % KB3;
  int k = jp >> 7, j = jp & 127;
  float v = (k < NSPL) ? loadf(W, ((size_t)(i * NSPL + k) * CC + j) * CC + c, bf)
                       : loadf(root, ((size_t)i * CC + j) * CC + c, bf);
  W16[idx] = f2h(v);
}
// final linear weight, bf16 hi/lo: Wsm[c][j] = finW[c][j]
__global__ void prep_wsmall(const void* __restrict__ finW, const int* __restrict__ flag,
                            ushort_t* __restrict__ Whi, ushort_t* __restrict__ Wlo) {
  int idx = blockIdx.x * blockDim.x + threadIdx.x;
  if (idx >= CC * CC) return;
  int bf = *flag;
  int c = idx >> 7, j = idx & 127;
  float v = loadf(finW, (size_t)c * CC + j, bf);
  ushort_t hi = f2b(v);
  Whi[idx] = hi;
  Wlo[idx] = f2b(v - b2f(hi));
}

// ---------------- h0 = emb[x] -> h16 (fp16) ----------------
__global__ void init_h(const int* __restrict__ x, const void* __restrict__ emb,
                       const int* __restrict__ flag, ushort_t* __restrict__ h16) {
  int idx = blockIdx.x * blockDim.x + threadIdx.x;   // over NPAD*128
  int c = idx & 127, n = idx >> 7;
  if (n >= NPAD) return;
  float v = (n < NN) ? loadf(emb, (size_t)x[n] * CC + c, *flag) : 0.0f;
  h16[idx] = f2h(v);
}

// ---------------- CSR build ----------------
__global__ void ideg_kernel(const int* __restrict__ ei, int* __restrict__ ideg, int E) {
  int e = blockIdx.x * blockDim.x + threadIdx.x;
  if (e < E) atomicAdd(&ideg[ei[E + e]], 1);
}
__global__ void rdeg_kernel(const int* __restrict__ ideg, float* __restrict__ deg,
                            float* __restrict__ rdeg) {
  int n = blockIdx.x * blockDim.x + threadIdx.x;
  if (n >= NPAD) return;
  float d = (n < NN) ? (float)ideg[n] : 0.0f;
  deg[n] = d;
  rdeg[n] = 1.0f / fmaxf(d, 1.0f);
}
// single-block scan, shfl-based (3 barriers per 1024-tile)
__global__ void scan_offs(const int* __restrict__ ideg, int* __restrict__ offs) {
  __shared__ int wsum[16];
  __shared__ int wpre[16];
  __shared__ int carry;
  int tid = threadIdx.x, lane = tid & 63, wid = tid >> 6;
  if (tid == 0) { carry = 0; offs[0] = 0; }
  __syncthreads();
  for (int base = 0; base < NN; base += 1024) {
    int v = (base + tid < NN) ? ideg[base + tid] : 0;
    int x = v;
#pragma unroll
    for (int s = 1; s < 64; s <<= 1) {
      int t = __shfl_up(x, s);
      if (lane >= s) x += t;
    }
    if (lane == 63) wsum[wid] = x;
    __syncthreads();
    if (tid == 0) {
      int run = carry;
#pragma unroll
      for (int k = 0; k < 16; ++k) { wpre[k] = run; run += wsum[k]; }
      carry = run;
    }
    __syncthreads();
    if (base + tid < NN) offs[base + tid + 1] = wpre[wid] + x;
    __syncthreads();
  }
}
// fill: erec = { src | base<<16 , {f0,f1} fp16 }  (one 8B record per edge)
__global__ void fill_csr(const int* __restrict__ ei, const void* __restrict__ eattr,
                         const int* __restrict__ flag, const int* __restrict__ offs,
                         int* __restrict__ cursor, uint2* __restrict__ erec, int E) {
  int e = blockIdx.x * blockDim.x + threadIdx.x;
  if (e >= E) return;
  int bf = *flag;
  int src = ei[e], dst = ei[E + e];
  float a0, a1;
  if (bf) {
    uint32_t ap = ((const uint32_t*)eattr)[e];
    a0 = b2f(ap & 0xffffu); a1 = b2f(ap >> 16);
  } else {
    float2 f = ((const float2*)eattr)[e];
    a0 = f.x; a1 = f.y;
  }
  float v0 = fminf(fmaxf(a0 * 4.0f, 0.0f), 4.0f);   // sanitize (NaN -> 0)
  float v1 = fminf(fmaxf(a1 * 4.0f, 0.0f), 4.0f);
  float lo0 = fminf(floorf(v0), 3.0f);
  float lo1 = fminf(floorf(v1), 3.0f);
  float f0 = v0 - lo0, f1 = v1 - lo1;
  int base = (int)lo0 + 5 * (int)lo1;
  int pos = atomicAdd(&cursor[dst], 1);
  int slot = offs[dst] + pos;
  union { _Float16 h[2]; uint32_t u; } pf;
  pf.h[0] = (_Float16)f0; pf.h[1] = (_Float16)f1;
  erec[slot] = make_uint2((uint32_t)src | ((uint32_t)base << 16), pf.u);
}

// ---------------- edge pass (register accumulators, no LDS) ----------------
// One wave per dst node. Wave processes one edge at a time -> base is wave-uniform ->
// uniform 16-way switch updates 4 of 25 float2 accumulators at COMPILE-TIME indices.
// Slot 25 of U = h16[n] * max(deg,1)  (root term folded into the U GEMM).
#define TAPC(B) case B: \
      acc[B].x += w00 * h0;     acc[B].y += w00 * h1; \
      acc[B+1].x += w10 * h0;   acc[B+1].y += w10 * h1; \
      acc[B+5].x += w01 * h0;   acc[B+5].y += w01 * h1; \
      acc[B+6].x += w11 * h0;   acc[B+6].y += w11 * h1; break;
#define PROC(RX, RY, HW) { \
    union { uint32_t u; _Float16 h[2]; } cf_, ch_; cf_.u = (RY); ch_.u = (HW); \
    float f0 = (float)cf_.h[0], f1 = (float)cf_.h[1]; \
    float h0 = (float)ch_.h[0], h1 = (float)ch_.h[1]; \
    float w11 = f0 * f1, w10 = f0 - w11, w01 = f1 - w11, w00 = 1.0f - f0 - f1 + w11; \
    switch (((RX) >> 16) & 31) { \
      TAPC(0) TAPC(1) TAPC(2) TAPC(3) TAPC(5) TAPC(6) TAPC(7) TAPC(8) \
      TAPC(10) TAPC(11) TAPC(12) TAPC(13) TAPC(15) TAPC(16) TAPC(17) TAPC(18) \
      default: break; } }

__global__ __launch_bounds__(256) void edge_u(
    const int* __restrict__ offs, const uint2* __restrict__ erec,
    const ushort_t* __restrict__ h16, const float* __restrict__ deg,
    ushort_t* __restrict__ U, int n0, int n1) {
  const int wv = threadIdx.x >> 6, l = threadIdx.x & 63;
  for (int n = n0 + blockIdx.x * 4 + wv; n < n1; n += gridDim.x * 4) {
    float2 acc[25];
#pragma unroll
    for (int k = 0; k < 25; ++k) acc[k] = make_float2(0.0f, 0.0f);
    int o0 = offs[n], o1 = offs[n + 1];
    int o = o0;
    if ((o & 1) && o < o1) {     // align to 16B for uint4 batches
      uint2 r = erec[o];
      uint32_t hw = *(const uint32_t*)(h16 + (size_t)(r.x & 0xffff) * CC + 2 * l);
      PROC(r.x, r.y, hw);
      ++o;
    }
    for (; o + 4 <= o1; o += 4) {
      uint4 rA = *(const uint4*)(erec + o);
      uint4 rB = *(const uint4*)(erec + o + 2);
      uint32_t hw0 = *(const uint32_t*)(h16 + (size_t)(rA.x & 0xffff) * CC + 2 * l);
      uint32_t hw1 = *(const uint32_t*)(h16 + (size_t)(rA.z & 0xffff) * CC + 2 * l);
      uint32_t hw2 = *(const uint32_t*)(h16 + (size_t)(rB.x & 0xffff) * CC + 2 * l);
      uint32_t hw3 = *(const uint32_t*)(h16 + (size_t)(rB.z & 0xffff) * CC + 2 * l);
      PROC(rA.x, rA.y, hw0);
      PROC(rA.z, rA.w, hw1);
      PROC(rB.x, rB.y, hw2);
      PROC(rB.z, rB.w, hw3);
    }
    for (; o < o1; ++o) {
      uint2 r = erec[o];
      uint32_t hw = *(const uint32_t*)(h16 + (size_t)(r.x & 0xffff) * CC + 2 * l);
      PROC(r.x, r.y, hw);
    }
    uint32_t* Ur = (uint32_t*)(U + (size_t)(n - n0) * KB3);
#pragma unroll
    for (int k = 0; k < 25; ++k) {
      union { _Float16 h[2]; uint32_t u; } pk;
      pk.h[0] = (_Float16)acc[k].x; pk.h[1] = (_Float16)acc[k].y;
      Ur[(k << 6) + l] = pk.u;
    }
    float s = fmaxf(deg[n], 1.0f);
    uint32_t hwn = *(const uint32_t*)(h16 + (size_t)n * CC + 2 * l);
    union { uint32_t u; _Float16 h[2]; } cn; cn.u = hwn;
    union { _Float16 h[2]; uint32_t u; } pn;
    pn.h[0] = (_Float16)((float)cn.h[0] * s);
    pn.h[1] = (_Float16)((float)cn.h[1] * s);
    Ur[(25 << 6) + l] = pn.u;
  }
}
#undef PROC
#undef TAPC

// ---------------- U GEMM (fp16): agg[n0+m][c] += sum_j U[m][j] * W16[c][j] ----------------
// K split across blockIdx.y (13 slots each); atomic += epilogue (agg pre-zeroed).
__global__ __launch_bounds__(256, 2) void gemm_u(
    const ushort_t* __restrict__ U, const ushort_t* __restrict__ B16,
    float* __restrict__ agg, int n0, int mvalid) {
  __shared__ char sm[65536];
  char* smA = sm;
  char* smB = sm + 32768;
  const int m0 = blockIdx.x * 128;
  const int kc0 = blockIdx.y * 13;
  const int kc1 = kc0 + 13;
  const int tid = threadIdx.x;
  const int w = tid >> 6, l = tid & 63;
  const int lr = l & 15, lg = l >> 4;
  const int wr = w >> 1, wc = w & 1;

  f32x4 acc[4][4] = {};
  for (int kc = kc0; kc < kc1; ++kc) {
    for (int i = 0; i < 8; ++i) {
      int row    = w * 32 + i * 4 + lg;
      int gchunk = lr ^ (row & 7);
      const ushort_t* gA = U + (size_t)(m0 + row) * KB3 + kc * 128 + gchunk * 8;
      const ushort_t* gB = B16 + (size_t)row * KB3 + kc * 128 + gchunk * 8;
      __builtin_amdgcn_global_load_lds(
          (const __attribute__((address_space(1))) void*)gA,
          (__attribute__((address_space(3))) void*)(smA + (w * 32 + i * 4) * 256), 16, 0, 0);
      __builtin_amdgcn_global_load_lds(
          (const __attribute__((address_space(1))) void*)gB,
          (__attribute__((address_space(3))) void*)(smB + (w * 32 + i * 4) * 256), 16, 0, 0);
    }
    __syncthreads();
    for (int kk = 0; kk < 4; ++kk) {
      f16x8 av[4], bv[4];
#pragma unroll
      for (int mi = 0; mi < 4; ++mi) {
        int row   = wr * 64 + mi * 16 + lr;
        int chunk = (kk * 4 + lg) ^ (row & 7);
        av[mi] = *(const f16x8*)(smA + row * 256 + chunk * 16);
      }
#pragma unroll
      for (int ni = 0; ni < 4; ++ni) {
        int row   = wc * 64 + ni * 16 + lr;
        int chunk = (kk * 4 + lg) ^ (row & 7);
        bv[ni] = *(const f16x8*)(smB + row * 256 + chunk * 16);
      }
#pragma unroll
      for (int mi = 0; mi < 4; ++mi)
#pragma unroll
        for (int ni = 0; ni < 4; ++ni)
          acc[mi][ni] = __builtin_amdgcn_mfma_f32_16x16x32_f16(av[mi], bv[ni], acc[mi][ni], 0, 0, 0);
    }
    __syncthreads();
  }
  const int colb = wc * 64;
#pragma unroll
  for (int mi = 0; mi < 4; ++mi) {
    int growbase = m0 + wr * 64 + mi * 16 + lg * 4;
#pragma unroll
    for (int ni = 0; ni < 4; ++ni) {
      int col = colb + ni * 16 + lr;
      f32x4 v = acc[mi][ni];
#pragma unroll
      for (int j = 0; j < 4; ++j) {
        int grow = growbase + j;
        if (grow < mvalid)
          unsafeAtomicAdd(agg + (size_t)(n0 + grow) * CC + col, v[j]);
      }
    }
  }
}

// ---------------- final GEMM over h2 (3-chunk bf16 split precision) + bias ----------------
__global__ __launch_bounds__(256, 2) void gemm_final(
    const ushort_t* __restrict__ A2,
    const ushort_t* __restrict__ Bhi, const ushort_t* __restrict__ Blo,
    const void* __restrict__ bias, const int* __restrict__ flag,
    void* __restrict__ Cout, int Mvalid) {
  __shared__ char sm[65536];
  char* smA = sm;
  char* smB = sm + 32768;
  const int m0 = blockIdx.x * 128;
  const int tid = threadIdx.x;
  const int w = tid >> 6, l = tid & 63;
  const int lr = l & 15, lg = l >> 4;
  const int wr = w >> 1, wc = w & 1;

  f32x4 acc[4][4] = {};
#pragma unroll
  for (int ch = 0; ch < 3; ++ch) {
    const ushort_t* Ab = A2 + (ch == 1 ? 128 : 0);
    const ushort_t* Bb = (ch == 2 ? Blo : Bhi);
    for (int i = 0; i < 8; ++i) {
      int row    = w * 32 + i * 4 + lg;
      int gchunk = lr ^ (row & 7);
      const ushort_t* gA = Ab + (size_t)(m0 + row) * 256 + gchunk * 8;
      const ushort_t* gB = Bb + (size_t)row * CC + gchunk * 8;
      __builtin_amdgcn_global_load_lds(
          (const __attribute__((address_space(1))) void*)gA,
          (__attribute__((address_space(3))) void*)(smA + (w * 32 + i * 4) * 256), 16, 0, 0);
      __builtin_amdgcn_global_load_lds(
          (const __attribute__((address_space(1))) void*)gB,
          (__attribute__((address_space(3))) void*)(smB + (w * 32 + i * 4) * 256), 16, 0, 0);
    }
    __syncthreads();
    for (int kk = 0; kk < 4; ++kk) {
      bf16x8 av[4], bv[4];
#pragma unroll
      for (int mi = 0; mi < 4; ++mi) {
        int row   = wr * 64 + mi * 16 + lr;
        int chunk = (kk * 4 + lg) ^ (row & 7);
        av[mi] = *(const bf16x8*)(smA + row * 256 + chunk * 16);
      }
#pragma unroll
      for (int ni = 0; ni < 4; ++ni) {
        int row   = wc * 64 + ni * 16 + lr;
        int chunk = (kk * 4 + lg) ^ (row & 7);
        bv[ni] = *(const bf16x8*)(smB + row * 256 + chunk * 16);
      }
#pragma unroll
      for (int mi = 0; mi < 4; ++mi)
#pragma unroll
        for (int ni = 0; ni < 4; ++ni)
          acc[mi][ni] = __builtin_amdgcn_mfma_f32_16x16x32_bf16(av[mi], bv[ni], acc[mi][ni], 0, 0, 0);
    }
    __syncthreads();
  }
  const int bf = *flag;
  const int colb = wc * 64;
#pragma unroll
  for (int mi = 0; mi < 4; ++mi) {
    int growbase = m0 + wr * 64 + mi * 16 + lg * 4;
#pragma unroll
    for (int ni = 0; ni < 4; ++ni) {
      int col = colb + ni * 16 + lr;
      float badd = loadf(bias, col, bf);
      f32x4 v = acc[mi][ni];
#pragma unroll
      for (int j = 0; j < 4; ++j) {
        int grow = growbase + j;
        if (grow < Mvalid) {
          float val = v[j] + badd;
          if (bf) ((ushort_t*)Cout)[(size_t)grow * CC + col] = f2b(val);
          else    ((float*)Cout)[(size_t)grow * CC + col] = val;
        }
      }
    }
  }
}

// ---------------- node: y = agg*rdeg + bias ; BN partial sums ----------------
__global__ __launch_bounds__(256) void node_bn(
    float* __restrict__ agg, const float* __restrict__ rdeg,
    const void* __restrict__ bias, int layer, const int* __restrict__ flag,
    float* __restrict__ bnsum, float* __restrict__ bnsq) {
  int c   = threadIdx.x & 127;
  int sub = threadIdx.x >> 7;
  float b = loadf(bias, (size_t)layer * CC + c, *flag);
  float lsum = 0.0f, lsq = 0.0f;
  for (int n = blockIdx.x * 2 + sub; n < NN; n += gridDim.x * 2) {
    float y = agg[(size_t)n * CC + c] * rdeg[n] + b;
    agg[(size_t)n * CC + c] = y;
    lsum += y; lsq += y * y;
  }
  __shared__ float ssum[256], ssq[256];
  ssum[threadIdx.x] = lsum; ssq[threadIdx.x] = lsq;
  __syncthreads();
  if (sub == 0) {
    unsafeAtomicAdd(&bnsum[c], ssum[c] + ssum[c + 128]);
    unsafeAtomicAdd(&bnsq[c],  ssq[c]  + ssq[c + 128]);
  }
}

__global__ void bn_final(const float* __restrict__ bnsum, const float* __restrict__ bnsq,
                         const void* __restrict__ gamma, const void* __restrict__ beta,
                         int layer, const int* __restrict__ flag,
                         float* __restrict__ scale, float* __restrict__ shift) {
  int c = threadIdx.x;
  int bf = *flag;
  float mean = bnsum[c] * (1.0f / NN);
  float var  = fmaxf(bnsq[c] * (1.0f / NN) - mean * mean, 0.0f);
  float sc = loadf(gamma, (size_t)layer * CC + c, bf) * rsqrtf(var + 1e-5f);
  scale[c] = sc;
  shift[c] = loadf(beta, (size_t)layer * CC + c, bf) - mean * sc;
}

template <bool RELU, bool WRITEH2>
__global__ void norm_kernel(const float* __restrict__ y, const float* __restrict__ scale,
                            const float* __restrict__ shift, ushort_t* __restrict__ h16,
                            ushort_t* __restrict__ h2) {
  int idx = blockIdx.x * blockDim.x + threadIdx.x;   // over NPAD*128
  int c = idx & 127, n = idx >> 7;
  if (n >= NPAD) return;
  float v = 0.0f;
  if (n < NN) {
    v = scale[c] * y[idx] + shift[c];
    if (RELU) v = fmaxf(v, 0.0f);
  }
  h16[idx] = f2h(v);
  if (WRITEH2) {
    ushort_t hi = f2b(v);
    h2[(size_t)n * 256 + c]       = hi;
    h2[(size_t)n * 256 + 128 + c] = f2b(v - b2f(hi));
  }
}

// ---------------- launch ----------------
extern "C" void kernel_launch(void* const* d_in, const int* in_sizes, int n_in,
                              void* d_out, int out_size, void* d_ws, size_t ws_size,
                              hipStream_t stream) {
  const int*  x     = (const int*)d_in[0];
  const int*  ei    = (const int*)d_in[1];
  const void* eattr = d_in[2];
  const void* emb   = d_in[3];
  const void* convW = d_in[4];
  const void* convR = d_in[5];
  const void* convB = d_in[6];
  const void* gamma = d_in[7];
  const void* beta  = d_in[8];
  const void* finW  = d_in[9];
  const void* finB  = d_in[10];
  const int E = in_sizes[1] / 2;

  char* ws = (char*)d_ws;
  size_t off = 0;
  auto alloc = [&](size_t bytes) -> char* {
    char* p = ws + off; off += (bytes + 255) & ~(size_t)255; return p;
  };
  int*      flag   = (int*)alloc(256);
  ushort_t* Wcat16 = (ushort_t*)alloc((size_t)LAYERS * CC * KB3 * 2);    // 2.56 MB
  ushort_t* WsmHi  = (ushort_t*)alloc((size_t)CC * CC * 2);              // 32 KB
  ushort_t* WsmLo  = (ushort_t*)alloc((size_t)CC * CC * 2);
  ushort_t* h2     = (ushort_t*)alloc((size_t)NPAD * 256 * 2);           // 25.6 MB
  ushort_t* h16    = (ushort_t*)alloc((size_t)NPAD * CC * 2);            // 12.8 MB
  float*    agg    = (float*)alloc((size_t)NPAD * CC * 4);               // 25.6 MB
  int*      ideg   = (int*)alloc((size_t)NPAD * 4);
  float*    deg    = (float*)alloc((size_t)NPAD * 4);
  float*    rdeg   = (float*)alloc((size_t)NPAD * 4);
  int*      offs   = (int*)alloc((size_t)(NN + 1) * 4);
  int*      cursor = (int*)alloc((size_t)NN * 4);
  uint2*    erec   = (uint2*)alloc((size_t)E * 8);                       // 12.8 MB
  float*    bnst   = (float*)alloc(4 * CC * 4);   // sum | sq | scale | shift

  // U chunk: rows of [KB3] fp16, adaptive to remaining ws
  size_t avail = (ws_size > off + 4096) ? (ws_size - off - 4096) : 0;
  long rows = (long)(avail / (KB3 * 2));
  rows &= ~127L;
  if (rows < 128) rows = 128;
  if (rows > NPAD) rows = NPAD;
  int nch = (int)((NPAD + rows - 1) / rows);
  rows = (((NPAD + nch - 1) / nch + 127) / 128) * 128;
  while ((long)nch * rows < NPAD) rows += 128;
  ushort_t* U = (ushort_t*)(ws + off);

  probe_dtype<<<1, 64, 0, stream>>>((const uint32_t*)emb, flag);
  hipMemsetAsync(ideg, 0, (size_t)NPAD * 4, stream);
  hipMemsetAsync(cursor, 0, (size_t)NN * 4, stream);
  prep_wcat<<<(LAYERS * CC * KB3 + 255) / 256, 256, 0, stream>>>(convW, convR, flag, Wcat16);
  prep_wsmall<<<(CC * CC + 255) / 256, 256, 0, stream>>>(finW, flag, WsmHi, WsmLo);
  init_h<<<(NPAD * CC) / 256, 256, 0, stream>>>(x, emb, flag, h16);
  ideg_kernel<<<(E + 255) / 256, 256, 0, stream>>>(ei, ideg, E);
  rdeg_kernel<<<(NPAD + 255) / 256, 256, 0, stream>>>(ideg, deg, rdeg);
  scan_offs<<<1, 1024, 0, stream>>>(ideg, offs);
  fill_csr<<<(E + 255) / 256, 256, 0, stream>>>(ei, eattr, flag, offs, cursor, erec, E);

  for (int i = 0; i < LAYERS; ++i) {
    hipMemsetAsync(agg, 0, (size_t)NPAD * CC * 4, stream);
    hipMemsetAsync(bnst, 0, 2 * CC * 4, stream);
    for (int ch = 0; ch < nch; ++ch) {
      int n0 = ch * (int)rows;
      int n1 = n0 + (int)rows; if (n1 > NPAD) n1 = NPAD;
      int n1v = n1 < NN ? n1 : NN;
      if (n1v > n0)
        edge_u<<<(n1v - n0 + 3) / 4, 256, 0, stream>>>(offs, erec, h16, deg, U, n0, n1v);
      gemm_u<<<dim3((n1 - n0) / 128, 2), 256, 0, stream>>>(
          U, Wcat16 + (size_t)i * CC * KB3, agg, n0, NN - n0);
    }
    node_bn<<<1024, 256, 0, stream>>>(agg, rdeg, convB, i, flag, bnst, bnst + 128);
    bn_final<<<1, 128, 0, stream>>>(bnst, bnst + 128, gamma, beta, i, flag,
                                    bnst + 256, bnst + 384);
    if (i < LAYERS - 1)
      norm_kernel<true, false><<<(NPAD * CC) / 256, 256, 0, stream>>>(
          agg, bnst + 256, bnst + 384, h16, h2);
    else
      norm_kernel<false, true><<<(NPAD * CC) / 256, 256, 0, stream>>>(
          agg, bnst + 256, bnst + 384, h16, h2);
  }
  gemm_final<<<dim3(MT, 1), 256, 0, stream>>>(
      h2, WsmHi, WsmLo, finB, flag, d_out, NN);
}